// Round 1
// baseline (970.388 us; speedup 1.0000x reference)
//
#include <hip/hip_runtime.h>
#include <math.h>

#define N_NODES 20000
#define N_EDGES 320000
#define NENT    2000
#define KNN_K   10

typedef __attribute__((ext_vector_type(4))) float f32x4;
typedef __attribute__((ext_vector_type(8))) short bf16x8;
typedef __attribute__((ext_vector_type(8))) unsigned short u16x8;
typedef __attribute__((ext_vector_type(4))) unsigned short u16x4;

__device__ __forceinline__ unsigned short f2bf(float f) {
  union { float f; unsigned u; } v; v.f = f;
  unsigned r = v.u + 0x7fffu + ((v.u >> 16) & 1u);
  return (unsigned short)(r >> 16);
}
__device__ __forceinline__ float sigmoidf(float x) {
  return 1.f / (1.f + __expf(-x));
}

// ---------------- h0 = concat(position, w_embed) -> bf16 ----------------
__global__ void k_build_h0(const float* __restrict__ pos, const float* __restrict__ wemb,
                           unsigned short* __restrict__ h0) {
  int i = blockIdx.x * blockDim.x + threadIdx.x;
  if (i >= N_NODES * 128) return;
  int n = i >> 7, c = i & 127;
  float v = (c < 2) ? pos[n * 2 + c] : wemb[n * 126 + (c - 2)];
  h0[i] = f2bf(v);
}

// ---------------- generic f32 -> bf16 (n multiple of 4) ----------------
__global__ void k_f2bf(const float* __restrict__ in, unsigned short* __restrict__ out, int n) {
  int i = blockIdx.x * blockDim.x + threadIdx.x;
  if (i * 4 >= n) return;
  f32x4 v = *(const f32x4*)(in + i * 4);
  u16x4 o;
  o[0] = f2bf(v[0]); o[1] = f2bf(v[1]); o[2] = f2bf(v[2]); o[3] = f2bf(v[3]);
  *(u16x4*)(out + i * 4) = o;
}

// ---------------- bf16 MFMA GEMM: C[M,Nn] = A[M,K] * B[Nn,K]^T ----------------
__global__ __launch_bounds__(256) void k_gemm_bt(
    const unsigned short* __restrict__ A, const unsigned short* __restrict__ B,
    float* __restrict__ C, int M, int Nn, int K) {
  __shared__ __align__(16) unsigned short As[128 * 64];
  __shared__ __align__(16) unsigned short Bs[128 * 64];
  const int bm = blockIdx.x * 128, bn = blockIdx.y * 128;
  const int t = threadIdx.x;
  const int l = t & 63, w = t >> 6;
  const int wr = w >> 1, wc = w & 1;
  f32x4 acc[4][4];
#pragma unroll
  for (int m = 0; m < 4; ++m)
#pragma unroll
    for (int n = 0; n < 4; ++n) acc[m][n] = (f32x4){0.f, 0.f, 0.f, 0.f};

  for (int kb = 0; kb < K; kb += 64) {
    __syncthreads();
#pragma unroll
    for (int i = 0; i < 4; ++i) {
      int c = t + 256 * i;         // 1024 16B-chunks per tile
      int row = c >> 3, cc = c & 7;
      int sw = cc ^ (row & 7);     // T2 xor-swizzle (granule)
      int ar = bm + row; if (ar > M - 1) ar = M - 1;
      *(f32x4*)&As[row * 64 + sw * 8] = *(const f32x4*)(A + (size_t)ar * K + kb + cc * 8);
      *(f32x4*)&Bs[row * 64 + sw * 8] = *(const f32x4*)(B + (size_t)(bn + row) * K + kb + cc * 8);
    }
    __syncthreads();
#pragma unroll
    for (int kk = 0; kk < 2; ++kk) {
      bf16x8 af[4], bfr[4];
#pragma unroll
      for (int m = 0; m < 4; ++m) {
        int row = wr * 64 + m * 16 + (l & 15);
        int g = (kk * 4 + (l >> 4)) ^ (row & 7);
        af[m] = *(const bf16x8*)&As[row * 64 + g * 8];
      }
#pragma unroll
      for (int n = 0; n < 4; ++n) {
        int row = wc * 64 + n * 16 + (l & 15);
        int g = (kk * 4 + (l >> 4)) ^ (row & 7);
        bfr[n] = *(const bf16x8*)&Bs[row * 64 + g * 8];
      }
#pragma unroll
      for (int m = 0; m < 4; ++m)
#pragma unroll
        for (int n = 0; n < 4; ++n)
          acc[m][n] = __builtin_amdgcn_mfma_f32_16x16x32_bf16(af[m], bfr[n], acc[m][n], 0, 0, 0);
    }
  }
#pragma unroll
  for (int m = 0; m < 4; ++m) {
    int r0 = bm + wr * 64 + m * 16 + ((l >> 4) << 2);
#pragma unroll
    for (int n = 0; n < 4; ++n) {
      int c0 = bn + wc * 64 + n * 16 + (l & 15);
#pragma unroll
      for (int r = 0; r < 4; ++r) {
        int row = r0 + r;
        if (row < M) C[(size_t)row * Nn + c0] = acc[m][n][r];
      }
    }
  }
}

// ---------------- el/er: per (node, head) dot(feat, al/ar) ----------------
__global__ void k_el_er(const float* __restrict__ feat, const float* __restrict__ al,
                        const float* __restrict__ ar, float* __restrict__ el,
                        float* __restrict__ er) {
  int wid = (blockIdx.x * blockDim.x + threadIdx.x) >> 6;
  if (wid >= N_NODES) return;
  int l = threadIdx.x & 63;
  int g = l >> 4, q = l & 15;
  const float* fr = feat + (size_t)wid * 512 + l * 8;
  const float* alp = al + g * 128 + q * 8;
  const float* arp = ar + g * 128 + q * 8;
  float sl = 0.f, sr = 0.f;
#pragma unroll
  for (int j = 0; j < 8; ++j) { float f = fr[j]; sl += f * alp[j]; sr += f * arp[j]; }
#pragma unroll
  for (int d = 1; d < 16; d <<= 1) { sl += __shfl_xor(sl, d); sr += __shfl_xor(sr, d); }
  if (q == 0) { el[wid * 4 + g] = sl; er[wid * 4 + g] = sr; }
}

// ---------------- CSR build ----------------
__global__ void k_hist(const int* __restrict__ dst, int* __restrict__ indeg) {
  int e = blockIdx.x * blockDim.x + threadIdx.x;
  if (e < N_EDGES) atomicAdd(&indeg[dst[e]], 1);
}
__global__ void k_scan(const int* __restrict__ indeg, int* __restrict__ indptr) {
  int l = threadIdx.x;  // 64 threads, one wave
  if (l == 0) indptr[0] = 0;
  int carry = 0;
  for (int base = 0; base < N_NODES; base += 64) {
    int idx = base + l;
    int v = (idx < N_NODES) ? indeg[idx] : 0;
#pragma unroll
    for (int d = 1; d < 64; d <<= 1) { int o = __shfl_up(v, d); if (l >= d) v += o; }
    if (idx < N_NODES) indptr[idx + 1] = carry + v;
    carry += __shfl(v, 63);
  }
}
__global__ void k_copy_i32(const int* __restrict__ in, int* __restrict__ out, int n) {
  int i = blockIdx.x * blockDim.x + threadIdx.x;
  if (i < n) out[i] = in[i];
}
__global__ void k_scatter(const int* __restrict__ src, const int* __restrict__ dst,
                          int* __restrict__ cursor, int* __restrict__ csr_src) {
  int e = blockIdx.x * blockDim.x + threadIdx.x;
  if (e < N_EDGES) {
    int p = atomicAdd(&cursor[dst[e]], 1);
    csr_src[p] = src[e];
  }
}

// ---------------- GAT edge-softmax + aggregation (wave per dst node) ----------------
template <bool FINAL>
__global__ void k_gat_agg(const float* __restrict__ feat, const float* __restrict__ hres,
                          const float* __restrict__ el, const float* __restrict__ er,
                          const int* __restrict__ indptr, const int* __restrict__ csr_src,
                          unsigned short* __restrict__ hnext, float* __restrict__ h3) {
  int wid = (blockIdx.x * blockDim.x + threadIdx.x) >> 6;
  if (wid >= N_NODES) return;
  int l = threadIdx.x & 63;
  int g = l >> 4;
  int beg = indptr[wid], end = indptr[wid + 1];
  f32x4 er4 = *(const f32x4*)(er + wid * 4);
  const float NI = -__builtin_inff();
  f32x4 mx = (f32x4){NI, NI, NI, NI};
  for (int j = beg + l; j < end; j += 64) {
    int s = csr_src[j];
    f32x4 el4 = *(const f32x4*)(el + s * 4);
#pragma unroll
    for (int h = 0; h < 4; ++h) {
      float v = el4[h] + er4[h];
      v = (v >= 0.f) ? v : 0.2f * v;
      mx[h] = fmaxf(mx[h], v);
    }
  }
#pragma unroll
  for (int d = 1; d < 64; d <<= 1) {
#pragma unroll
    for (int h = 0; h < 4; ++h) mx[h] = fmaxf(mx[h], __shfl_xor(mx[h], d));
  }
  float m_g = mx[g];
  float er_g = er4[g];
  float asum = 0.f;
  float acc[8];
#pragma unroll
  for (int j = 0; j < 8; ++j) acc[j] = 0.f;
  for (int j = beg; j < end; ++j) {
    int s = csr_src[j];
    float ev = el[s * 4 + g] + er_g;
    ev = (ev >= 0.f) ? ev : 0.2f * ev;
    float p = __expf(ev - m_g);
    asum += p;
    const float* fs = feat + (size_t)s * 512 + l * 8;
    f32x4 f0 = *(const f32x4*)fs;
    f32x4 f1 = *(const f32x4*)(fs + 4);
    acc[0] += p * f0[0]; acc[1] += p * f0[1]; acc[2] += p * f0[2]; acc[3] += p * f0[3];
    acc[4] += p * f1[0]; acc[5] += p * f1[1]; acc[6] += p * f1[2]; acc[7] += p * f1[3];
  }
  float inv = (end > beg) ? 1.f / asum : 1.f;
  const float* hr = hres + (size_t)wid * 512 + l * 8;
  float o[8];
#pragma unroll
  for (int j = 0; j < 8; ++j) o[j] = acc[j] * inv + hr[j];
  if constexpr (!FINAL) {
    u16x8 ob;
#pragma unroll
    for (int j = 0; j < 8; ++j) ob[j] = f2bf(fmaxf(o[j], 0.f));
    *(u16x8*)(hnext + (size_t)wid * 512 + l * 8) = ob;
  } else {
#pragma unroll
    for (int j = 0; j < 8; ++j) {
      float v = o[j];
      v += __shfl_xor(v, 16);
      v += __shfl_xor(v, 32);
      o[j] = v * 0.25f;
    }
    if (g == 0) {
      f32x4 o0 = (f32x4){o[0], o[1], o[2], o[3]};
      f32x4 o1 = (f32x4){o[4], o[5], o[6], o[7]};
      *(f32x4*)(h3 + (size_t)wid * 128 + (l & 15) * 8) = o0;
      *(f32x4*)(h3 + (size_t)wid * 128 + (l & 15) * 8 + 4) = o1;
    }
  }
}

// ---------------- fused groups_score: |h3[src]-h3[dst]| -> MLP -> sigmoid ----------------
__global__ __launch_bounds__(256) void k_groups(
    const float* __restrict__ h3, const int* __restrict__ src, const int* __restrict__ dst,
    const float* __restrict__ Wg1, const float* __restrict__ bg1,
    const float* __restrict__ Wg2, const float* __restrict__ bg2,
    float* __restrict__ out) {
  __shared__ __align__(16) unsigned short Xs[128 * 128];
  __shared__ __align__(16) unsigned short Ws[128 * 128];
  const int t = threadIdx.x;
  const int l = t & 63, w = t >> 6, wr = w >> 1, wc = w & 1;
  const int e0 = blockIdx.x * 128;
  {
    int r = t >> 1, hf = t & 1;
    int e = e0 + r;
    const float* pa = h3 + (size_t)src[e] * 128 + hf * 64;
    const float* pb = h3 + (size_t)dst[e] * 128 + hf * 64;
    const float* pw = Wg1 + (size_t)r * 128 + hf * 64;
#pragma unroll
    for (int c = 0; c < 64; c += 8) {
      f32x4 a0 = *(const f32x4*)(pa + c), a1 = *(const f32x4*)(pa + c + 4);
      f32x4 b0 = *(const f32x4*)(pb + c), b1 = *(const f32x4*)(pb + c + 4);
      f32x4 w0 = *(const f32x4*)(pw + c), w1 = *(const f32x4*)(pw + c + 4);
      u16x8 xv, wv;
#pragma unroll
      for (int j = 0; j < 4; ++j) {
        xv[j] = f2bf(fabsf(a0[j] - b0[j]));
        xv[j + 4] = f2bf(fabsf(a1[j] - b1[j]));
        wv[j] = f2bf(w0[j]);
        wv[j + 4] = f2bf(w1[j]);
      }
      int gb = hf * 8 + (c >> 3);
      *(u16x8*)&Xs[r * 128 + (gb ^ (r & 15)) * 8] = xv;
      *(u16x8*)&Ws[r * 128 + (gb ^ (r & 15)) * 8] = wv;
    }
  }
  __syncthreads();
  f32x4 acc[4][4];
#pragma unroll
  for (int m = 0; m < 4; ++m)
#pragma unroll
    for (int n = 0; n < 4; ++n) acc[m][n] = (f32x4){0.f, 0.f, 0.f, 0.f};
#pragma unroll
  for (int kk = 0; kk < 4; ++kk) {
    bf16x8 af[4], bfr[4];
#pragma unroll
    for (int m = 0; m < 4; ++m) {
      int row = wr * 64 + m * 16 + (l & 15);
      int gsw = (kk * 4 + (l >> 4)) ^ (row & 15);
      af[m] = *(const bf16x8*)&Xs[row * 128 + gsw * 8];
    }
#pragma unroll
    for (int n = 0; n < 4; ++n) {
      int row = wc * 64 + n * 16 + (l & 15);
      int gsw = (kk * 4 + (l >> 4)) ^ (row & 15);
      bfr[n] = *(const bf16x8*)&Ws[row * 128 + gsw * 8];
    }
#pragma unroll
    for (int m = 0; m < 4; ++m)
#pragma unroll
      for (int n = 0; n < 4; ++n)
        acc[m][n] = __builtin_amdgcn_mfma_f32_16x16x32_bf16(af[m], bfr[n], acc[m][n], 0, 0, 0);
  }
  float part[4][4];
#pragma unroll
  for (int m = 0; m < 4; ++m)
#pragma unroll
    for (int r = 0; r < 4; ++r) part[m][r] = 0.f;
#pragma unroll
  for (int n = 0; n < 4; ++n) {
    int col = wc * 64 + n * 16 + (l & 15);
    float b1 = bg1[col], w2 = Wg2[col];
#pragma unroll
    for (int m = 0; m < 4; ++m)
#pragma unroll
      for (int r = 0; r < 4; ++r) {
        float y = fmaxf(acc[m][n][r] + b1, 0.f);
        part[m][r] += y * w2;
      }
  }
#pragma unroll
  for (int d = 1; d < 16; d <<= 1)
#pragma unroll
    for (int m = 0; m < 4; ++m)
#pragma unroll
      for (int r = 0; r < 4; ++r) part[m][r] += __shfl_xor(part[m][r], d);
  __syncthreads();  // safe to alias Xs now
  float* sc = (float*)Xs;
  if ((l & 15) == 0) {
#pragma unroll
    for (int m = 0; m < 4; ++m)
#pragma unroll
      for (int r = 0; r < 4; ++r)
        sc[wc * 128 + wr * 64 + m * 16 + (l >> 4) * 4 + r] = part[m][r];
  }
  __syncthreads();
  if (t < 128) {
    float logit = sc[t] + sc[128 + t] + bg2[0];
    out[e0 + t] = sigmoidf(logit);
  }
}

// ---------------- entity segment sums ----------------
__global__ void k_ent_scatter(const float* __restrict__ h3, const float* __restrict__ pos,
                              const int* __restrict__ entity, float* __restrict__ ent_sum,
                              float* __restrict__ pos_sum, float* __restrict__ cnt) {
  int i = blockIdx.x * blockDim.x + threadIdx.x;
  if (i >= N_NODES * 32) return;
  int n = i >> 5, c = i & 31;
  int e = entity[n];
  f32x4 v = *(const f32x4*)(h3 + (size_t)n * 128 + c * 4);
  atomicAdd(&ent_sum[e * 128 + c * 4 + 0], v[0]);
  atomicAdd(&ent_sum[e * 128 + c * 4 + 1], v[1]);
  atomicAdd(&ent_sum[e * 128 + c * 4 + 2], v[2]);
  atomicAdd(&ent_sum[e * 128 + c * 4 + 3], v[3]);
  if (c == 0) {
    atomicAdd(&pos_sum[e * 2 + 0], pos[n * 2 + 0]);
    atomicAdd(&pos_sum[e * 2 + 1], pos[n * 2 + 1]);
    atomicAdd(&cnt[e], 1.f);
  }
}

__global__ void k_entity_states(const float* __restrict__ ent_sum, const float* __restrict__ We,
                                const float* __restrict__ be, float* __restrict__ es) {
  int i = blockIdx.x * blockDim.x + threadIdx.x;
  if (i >= NENT * 128) return;
  int e = i >> 7, j = i & 127;
  const float* x = ent_sum + (size_t)e * 128;
  const float* wrow = We + (size_t)j * 128;
  float s = be[j];
  for (int k = 0; k < 128; k += 4) {
    f32x4 xv = *(const f32x4*)(x + k);
    f32x4 wv = *(const f32x4*)(wrow + k);
    s += xv[0] * wv[0] + xv[1] * wv[1] + xv[2] * wv[2] + xv[3] * wv[3];
  }
  es[i] = s;
}

__global__ void k_entity_class(const float* __restrict__ es, const float* __restrict__ Wc,
                               const float* __restrict__ bc, float* __restrict__ out) {
  int i = blockIdx.x * blockDim.x + threadIdx.x;
  if (i >= NENT * 4) return;
  int e = i >> 2, c = i & 3;
  const float* x = es + (size_t)e * 128;
  const float* wrow = Wc + (size_t)c * 128;
  float s = bc[c];
  for (int k = 0; k < 128; ++k) s += x[k] * wrow[k];
  out[i] = sigmoidf(s);
}

__global__ void k_entity_pos(const float* __restrict__ pos_sum, const float* __restrict__ cnt,
                             float* __restrict__ outpos, float* __restrict__ wspos) {
  int e = blockIdx.x * blockDim.x + threadIdx.x;
  if (e >= NENT) return;
  float c = fmaxf(cnt[e], 1.f);
  float x = pos_sum[e * 2] / c, y = pos_sum[e * 2 + 1] / c;
  outpos[e * 2] = x; outpos[e * 2 + 1] = y;
  wspos[e * 2] = x; wspos[e * 2 + 1] = y;
}

// ---------------- exact knn (K smallest d2, ties -> smaller index) ----------------
__global__ __launch_bounds__(256) void k_knn(const float* __restrict__ entpos,
                                             int* __restrict__ knn) {
  __shared__ float d2row[NENT];
  __shared__ float rv[256];
  __shared__ int ri[256];
  int i = blockIdx.x, t = threadIdx.x;
  float px = entpos[i * 2], py = entpos[i * 2 + 1];
  for (int j = t; j < NENT; j += 256) {
    float dx = px - entpos[j * 2], dy = py - entpos[j * 2 + 1];
    d2row[j] = __fadd_rn(__fmul_rn(dx, dx), __fmul_rn(dy, dy));
  }
  __syncthreads();
  for (int k = 0; k < KNN_K; ++k) {
    float bv = __builtin_inff(); int bi = 0x7fffffff;
    for (int j = t; j < NENT; j += 256) {
      float v = d2row[j];
      if (v < bv) { bv = v; bi = j; }
    }
    rv[t] = bv; ri[t] = bi;
    __syncthreads();
    for (int s = 128; s > 0; s >>= 1) {
      if (t < s) {
        if (rv[t + s] < rv[t] || (rv[t + s] == rv[t] && ri[t + s] < ri[t])) {
          rv[t] = rv[t + s]; ri[t] = ri[t + s];
        }
      }
      __syncthreads();
    }
    if (t == 0) { knn[i * KNN_K + k] = ri[0]; d2row[ri[0]] = __builtin_inff(); }
    __syncthreads();
  }
}

// ---------------- link MLP (wave per pair) ----------------
__global__ void k_link(const float* __restrict__ es, const int* __restrict__ knn,
                       const float* __restrict__ Wl1, const float* __restrict__ bl1,
                       const float* __restrict__ Wl2, const float* __restrict__ bl2,
                       float* __restrict__ out) {
  int wid = (blockIdx.x * blockDim.x + threadIdx.x) >> 6;
  if (wid >= NENT * KNN_K) return;
  int l = threadIdx.x & 63;
  int de = wid / KNN_K;
  int se = knn[wid];
  float x0 = fabsf(es[(size_t)se * 128 + 2 * l] - es[(size_t)de * 128 + 2 * l]);
  float x1 = fabsf(es[(size_t)se * 128 + 2 * l + 1] - es[(size_t)de * 128 + 2 * l + 1]);
  float yl = bl1[l], yh = bl1[l + 64];
  for (int k = 0; k < 128; ++k) {
    float pick = (k & 1) ? x1 : x0;
    float xv = __shfl(pick, k >> 1);
    yl += Wl1[(size_t)l * 128 + k] * xv;
    yh += Wl1[(size_t)(l + 64) * 128 + k] * xv;
  }
  float s = fmaxf(yl, 0.f) * Wl2[l] + fmaxf(yh, 0.f) * Wl2[l + 64];
#pragma unroll
  for (int d = 1; d < 64; d <<= 1) s += __shfl_xor(s, d);
  if (l == 0) out[wid] = sigmoidf(s + bl2[0]);
}

// =======================================================================
extern "C" void kernel_launch(void* const* d_in, const int* in_sizes, int n_in,
                              void* d_out, int out_size, void* d_ws, size_t ws_size,
                              hipStream_t stream) {
  const float* position = (const float*)d_in[0];
  const float* w_embed  = (const float*)d_in[1];
  const int*   src      = (const int*)d_in[2];
  const int*   dst      = (const int*)d_in[3];
  const int*   entity   = (const int*)d_in[4];
  const float* W1 = (const float*)d_in[5];
  const float* al1 = (const float*)d_in[6];
  const float* ar1 = (const float*)d_in[7];
  const float* Wr1 = (const float*)d_in[8];
  const float* W2 = (const float*)d_in[9];
  const float* al2 = (const float*)d_in[10];
  const float* ar2 = (const float*)d_in[11];
  const float* Wr2 = (const float*)d_in[12];
  const float* W3 = (const float*)d_in[13];
  const float* al3 = (const float*)d_in[14];
  const float* ar3 = (const float*)d_in[15];
  const float* Wr3 = (const float*)d_in[16];
  const float* Wg1 = (const float*)d_in[17];
  const float* bg1 = (const float*)d_in[18];
  const float* Wg2 = (const float*)d_in[19];
  const float* bg2 = (const float*)d_in[20];
  const float* We  = (const float*)d_in[21];
  const float* be  = (const float*)d_in[22];
  const float* Wl1 = (const float*)d_in[23];
  const float* bl1 = (const float*)d_in[24];
  const float* Wl2 = (const float*)d_in[25];
  const float* bl2 = (const float*)d_in[26];
  const float* Wc  = (const float*)d_in[27];
  const float* bc  = (const float*)d_in[28];

  float* out_groups = (float*)d_out;
  float* out_class  = out_groups + N_EDGES;
  float* out_pos    = out_class + NENT * 4;
  float* out_link   = out_pos + NENT * 2;

  char* ws = (char*)d_ws;
  size_t off = 0;
  auto carve = [&](size_t bytes) -> char* {
    char* p = ws + off;
    off = (off + bytes + 255) & ~(size_t)255;
    return p;
  };
  float* feat = (float*)carve((size_t)N_NODES * 512 * 4);
  float* hres = (float*)carve((size_t)N_NODES * 512 * 4);
  unsigned short* hA = (unsigned short*)carve((size_t)N_NODES * 512 * 2);
  unsigned short* hB = (unsigned short*)carve((size_t)N_NODES * 512 * 2);
  unsigned short* wbf = (unsigned short*)carve(512 * 512 * 2);
  unsigned short* wrbf = (unsigned short*)carve(512 * 512 * 2);
  float* el = (float*)carve((size_t)N_NODES * 4 * 4);
  float* er = (float*)carve((size_t)N_NODES * 4 * 4);
  int* indeg = (int*)carve((size_t)N_NODES * 4);
  int* indptr = (int*)carve((size_t)(N_NODES + 1) * 4);
  int* cursor = (int*)carve((size_t)N_NODES * 4);
  int* csr_src = (int*)carve((size_t)N_EDGES * 4);
  float* h3 = (float*)carve((size_t)N_NODES * 128 * 4);
  float* ent_sum = (float*)carve((size_t)NENT * 128 * 4);
  float* pos_sum = (float*)carve((size_t)NENT * 2 * 4);
  float* cnt = (float*)carve((size_t)NENT * 4);
  float* es = (float*)carve((size_t)NENT * 128 * 4);
  float* wspos = (float*)carve((size_t)NENT * 2 * 4);
  int* knn = (int*)carve((size_t)NENT * KNN_K * 4);

  // ---- CSR over dst (shared by all 3 GAT layers) ----
  hipMemsetAsync(indeg, 0, (size_t)N_NODES * 4, stream);
  k_hist<<<(N_EDGES + 255) / 256, 256, 0, stream>>>(dst, indeg);
  k_scan<<<1, 64, 0, stream>>>(indeg, indptr);
  k_copy_i32<<<(N_NODES + 255) / 256, 256, 0, stream>>>(indptr, cursor, N_NODES);
  k_scatter<<<(N_EDGES + 255) / 256, 256, 0, stream>>>(src, dst, cursor, csr_src);

  k_build_h0<<<(N_NODES * 128 + 255) / 256, 256, 0, stream>>>(position, w_embed, hA);

  dim3 ggrid((N_NODES + 127) / 128, 4), gblk(256);

  // ---- layer 1 (K=128) ----
  k_f2bf<<<(512 * 128 / 4 + 255) / 256, 256, 0, stream>>>(W1, wbf, 512 * 128);
  k_f2bf<<<(512 * 128 / 4 + 255) / 256, 256, 0, stream>>>(Wr1, wrbf, 512 * 128);
  k_gemm_bt<<<ggrid, gblk, 0, stream>>>(hA, wbf, feat, N_NODES, 512, 128);
  k_gemm_bt<<<ggrid, gblk, 0, stream>>>(hA, wrbf, hres, N_NODES, 512, 128);
  k_el_er<<<5000, 256, 0, stream>>>(feat, al1, ar1, el, er);
  k_gat_agg<false><<<5000, 256, 0, stream>>>(feat, hres, el, er, indptr, csr_src, hB, nullptr);

  // ---- layer 2 (K=512) ----
  k_f2bf<<<(512 * 512 / 4 + 255) / 256, 256, 0, stream>>>(W2, wbf, 512 * 512);
  k_f2bf<<<(512 * 512 / 4 + 255) / 256, 256, 0, stream>>>(Wr2, wrbf, 512 * 512);
  k_gemm_bt<<<ggrid, gblk, 0, stream>>>(hB, wbf, feat, N_NODES, 512, 512);
  k_gemm_bt<<<ggrid, gblk, 0, stream>>>(hB, wrbf, hres, N_NODES, 512, 512);
  k_el_er<<<5000, 256, 0, stream>>>(feat, al2, ar2, el, er);
  k_gat_agg<false><<<5000, 256, 0, stream>>>(feat, hres, el, er, indptr, csr_src, hA, nullptr);

  // ---- layer 3 (K=512, no relu, head-mean) ----
  k_f2bf<<<(512 * 512 / 4 + 255) / 256, 256, 0, stream>>>(W3, wbf, 512 * 512);
  k_f2bf<<<(512 * 512 / 4 + 255) / 256, 256, 0, stream>>>(Wr3, wrbf, 512 * 512);
  k_gemm_bt<<<ggrid, gblk, 0, stream>>>(hA, wbf, feat, N_NODES, 512, 512);
  k_gemm_bt<<<ggrid, gblk, 0, stream>>>(hA, wrbf, hres, N_NODES, 512, 512);
  k_el_er<<<5000, 256, 0, stream>>>(feat, al3, ar3, el, er);
  k_gat_agg<true><<<5000, 256, 0, stream>>>(feat, hres, el, er, indptr, csr_src, nullptr, h3);

  // ---- groups_score (fused) ----
  k_groups<<<N_EDGES / 128, 256, 0, stream>>>(h3, src, dst, Wg1, bg1, Wg2, bg2, out_groups);

  // ---- entity path ----
  hipMemsetAsync(ent_sum, 0, (size_t)NENT * 128 * 4, stream);
  hipMemsetAsync(pos_sum, 0, (size_t)NENT * 2 * 4, stream);
  hipMemsetAsync(cnt, 0, (size_t)NENT * 4, stream);
  k_ent_scatter<<<(N_NODES * 32 + 255) / 256, 256, 0, stream>>>(h3, position, entity, ent_sum,
                                                                pos_sum, cnt);
  k_entity_states<<<(NENT * 128 + 255) / 256, 256, 0, stream>>>(ent_sum, We, be, es);
  k_entity_class<<<(NENT * 4 + 255) / 256, 256, 0, stream>>>(es, Wc, bc, out_class);
  k_entity_pos<<<(NENT + 255) / 256, 256, 0, stream>>>(pos_sum, cnt, out_pos, wspos);
  k_knn<<<NENT, 256, 0, stream>>>(wspos, knn);
  k_link<<<(NENT * KNN_K * 64 + 255) / 256, 256, 0, stream>>>(es, knn, Wl1, bl1, Wl2, bl2,
                                                              out_link);
}

// Round 2
// 843.880 us; speedup vs baseline: 1.1499x; 1.1499x over previous
//
#include <hip/hip_runtime.h>
#include <math.h>

#define N_NODES 20000
#define N_EDGES 320000
#define NENT    2000
#define KNN_K   10

typedef __attribute__((ext_vector_type(4))) float f32x4;
typedef __attribute__((ext_vector_type(8))) short bf16x8;
typedef __attribute__((ext_vector_type(8))) unsigned short u16x8;
typedef __attribute__((ext_vector_type(4))) unsigned short u16x4;

__device__ __forceinline__ unsigned short f2bf(float f) {
  union { float f; unsigned u; } v; v.f = f;
  unsigned r = v.u + 0x7fffu + ((v.u >> 16) & 1u);
  return (unsigned short)(r >> 16);
}
__device__ __forceinline__ float sigmoidf(float x) {
  return 1.f / (1.f + __expf(-x));
}

// ---------------- h0 = concat(position, w_embed) -> bf16 ----------------
__global__ void k_build_h0(const float* __restrict__ pos, const float* __restrict__ wemb,
                           unsigned short* __restrict__ h0) {
  int i = blockIdx.x * blockDim.x + threadIdx.x;
  if (i >= N_NODES * 128) return;
  int n = i >> 7, c = i & 127;
  float v = (c < 2) ? pos[n * 2 + c] : wemb[n * 126 + (c - 2)];
  h0[i] = f2bf(v);
}

// ---------------- generic f32 -> bf16 (n multiple of 4) ----------------
__global__ void k_f2bf(const float* __restrict__ in, unsigned short* __restrict__ out, int n) {
  int i = blockIdx.x * blockDim.x + threadIdx.x;
  if (i * 4 >= n) return;
  f32x4 v = *(const f32x4*)(in + i * 4);
  u16x4 o;
  o[0] = f2bf(v[0]); o[1] = f2bf(v[1]); o[2] = f2bf(v[2]); o[3] = f2bf(v[3]);
  *(u16x4*)(out + i * 4) = o;
}

// ---------------- bf16 MFMA GEMM: C[M,Nn] = A[M,K] * B[Nn,K]^T ----------------
__global__ __launch_bounds__(256) void k_gemm_bt(
    const unsigned short* __restrict__ A, const unsigned short* __restrict__ B,
    float* __restrict__ C, int M, int Nn, int K) {
  __shared__ __align__(16) unsigned short As[128 * 64];
  __shared__ __align__(16) unsigned short Bs[128 * 64];
  const int bm = blockIdx.x * 128, bn = blockIdx.y * 128;
  const int t = threadIdx.x;
  const int l = t & 63, w = t >> 6;
  const int wr = w >> 1, wc = w & 1;
  f32x4 acc[4][4];
#pragma unroll
  for (int m = 0; m < 4; ++m)
#pragma unroll
    for (int n = 0; n < 4; ++n) acc[m][n] = (f32x4){0.f, 0.f, 0.f, 0.f};

  for (int kb = 0; kb < K; kb += 64) {
    __syncthreads();
#pragma unroll
    for (int i = 0; i < 4; ++i) {
      int c = t + 256 * i;         // 1024 16B-chunks per tile
      int row = c >> 3, cc = c & 7;
      int sw = cc ^ (row & 7);     // T2 xor-swizzle (granule)
      int ar = bm + row; if (ar > M - 1) ar = M - 1;
      *(f32x4*)&As[row * 64 + sw * 8] = *(const f32x4*)(A + (size_t)ar * K + kb + cc * 8);
      *(f32x4*)&Bs[row * 64 + sw * 8] = *(const f32x4*)(B + (size_t)(bn + row) * K + kb + cc * 8);
    }
    __syncthreads();
#pragma unroll
    for (int kk = 0; kk < 2; ++kk) {
      bf16x8 af[4], bfr[4];
#pragma unroll
      for (int m = 0; m < 4; ++m) {
        int row = wr * 64 + m * 16 + (l & 15);
        int g = (kk * 4 + (l >> 4)) ^ (row & 7);
        af[m] = *(const bf16x8*)&As[row * 64 + g * 8];
      }
#pragma unroll
      for (int n = 0; n < 4; ++n) {
        int row = wc * 64 + n * 16 + (l & 15);
        int g = (kk * 4 + (l >> 4)) ^ (row & 7);
        bfr[n] = *(const bf16x8*)&Bs[row * 64 + g * 8];
      }
#pragma unroll
      for (int m = 0; m < 4; ++m)
#pragma unroll
        for (int n = 0; n < 4; ++n)
          acc[m][n] = __builtin_amdgcn_mfma_f32_16x16x32_bf16(af[m], bfr[n], acc[m][n], 0, 0, 0);
    }
  }
#pragma unroll
  for (int m = 0; m < 4; ++m) {
    int r0 = bm + wr * 64 + m * 16 + ((l >> 4) << 2);
#pragma unroll
    for (int n = 0; n < 4; ++n) {
      int c0 = bn + wc * 64 + n * 16 + (l & 15);
#pragma unroll
      for (int r = 0; r < 4; ++r) {
        int row = r0 + r;
        if (row < M) C[(size_t)row * Nn + c0] = acc[m][n][r];
      }
    }
  }
}

// ---------------- el/er: per (node, head) dot(feat, al/ar) ----------------
__global__ void k_el_er(const float* __restrict__ feat, const float* __restrict__ al,
                        const float* __restrict__ ar, float* __restrict__ el,
                        float* __restrict__ er) {
  int wid = (blockIdx.x * blockDim.x + threadIdx.x) >> 6;
  if (wid >= N_NODES) return;
  int l = threadIdx.x & 63;
  int g = l >> 4, q = l & 15;
  const float* fr = feat + (size_t)wid * 512 + l * 8;
  const float* alp = al + g * 128 + q * 8;
  const float* arp = ar + g * 128 + q * 8;
  float sl = 0.f, sr = 0.f;
#pragma unroll
  for (int j = 0; j < 8; ++j) { float f = fr[j]; sl += f * alp[j]; sr += f * arp[j]; }
#pragma unroll
  for (int d = 1; d < 16; d <<= 1) { sl += __shfl_xor(sl, d); sr += __shfl_xor(sr, d); }
  if (q == 0) { el[wid * 4 + g] = sl; er[wid * 4 + g] = sr; }
}

// ---------------- CSR build ----------------
__global__ void k_hist(const int* __restrict__ dst, int* __restrict__ indeg) {
  int e = blockIdx.x * blockDim.x + threadIdx.x;
  if (e < N_EDGES) atomicAdd(&indeg[dst[e]], 1);
}

// single-block 1024-thread scan: indptr (exclusive->inclusive) + cursor init
__global__ __launch_bounds__(1024) void k_scan_fast(const int* __restrict__ indeg,
                                                    int* __restrict__ indptr,
                                                    int* __restrict__ cursor) {
  __shared__ int wsum[16];
  const int t = threadIdx.x;
  const int l = t & 63, w = t >> 6;
  const int CH = 20;  // 1024*20 >= 20000
  int base = t * CH;
  int vals[CH];
  int s = 0;
#pragma unroll
  for (int i = 0; i < CH; ++i) {
    int idx = base + i;
    int v = (idx < N_NODES) ? indeg[idx] : 0;
    vals[i] = v;
    s += v;
  }
  int ss = s;
#pragma unroll
  for (int d = 1; d < 64; d <<= 1) { int o = __shfl_up(ss, d); if (l >= d) ss += o; }
  if (l == 63) wsum[w] = ss;
  __syncthreads();
  if (t < 16) {
    int v = wsum[t];
#pragma unroll
    for (int d = 1; d < 16; d <<= 1) { int o = __shfl_up(v, d); if (t >= d) v += o; }
    wsum[t] = v;
  }
  __syncthreads();
  int run = ((w > 0) ? wsum[w - 1] : 0) + ss - s;  // exclusive prefix of this thread
  if (t == 0) indptr[0] = 0;
#pragma unroll
  for (int i = 0; i < CH; ++i) {
    int idx = base + i;
    if (idx < N_NODES) {
      cursor[idx] = run;
      run += vals[i];
      indptr[idx + 1] = run;
    }
  }
}

__global__ void k_scatter(const int* __restrict__ src, const int* __restrict__ dst,
                          int* __restrict__ cursor, int* __restrict__ csr_src) {
  int e = blockIdx.x * blockDim.x + threadIdx.x;
  if (e < N_EDGES) {
    int p = atomicAdd(&cursor[dst[e]], 1);
    csr_src[p] = src[e];
  }
}

// ---------------- GAT edge-softmax + aggregation (wave per dst node) ----------------
template <bool FINAL>
__global__ void k_gat_agg(const float* __restrict__ feat, const float* __restrict__ hres,
                          const float* __restrict__ el, const float* __restrict__ er,
                          const int* __restrict__ indptr, const int* __restrict__ csr_src,
                          unsigned short* __restrict__ hnext, float* __restrict__ h3) {
  int wid = (blockIdx.x * blockDim.x + threadIdx.x) >> 6;
  if (wid >= N_NODES) return;
  int l = threadIdx.x & 63;
  int g = l >> 4;
  int beg = indptr[wid], end = indptr[wid + 1];
  f32x4 er4 = *(const f32x4*)(er + wid * 4);
  const float NI = -__builtin_inff();
  f32x4 mx = (f32x4){NI, NI, NI, NI};
  for (int j = beg + l; j < end; j += 64) {
    int s = csr_src[j];
    f32x4 el4 = *(const f32x4*)(el + s * 4);
#pragma unroll
    for (int h = 0; h < 4; ++h) {
      float v = el4[h] + er4[h];
      v = (v >= 0.f) ? v : 0.2f * v;
      mx[h] = fmaxf(mx[h], v);
    }
  }
#pragma unroll
  for (int d = 1; d < 64; d <<= 1) {
#pragma unroll
    for (int h = 0; h < 4; ++h) mx[h] = fmaxf(mx[h], __shfl_xor(mx[h], d));
  }
  float m_g = mx[g];
  float er_g = er4[g];
  float asum = 0.f;
  float acc[8];
#pragma unroll
  for (int j = 0; j < 8; ++j) acc[j] = 0.f;
  for (int j = beg; j < end; ++j) {
    int s = csr_src[j];
    float ev = el[s * 4 + g] + er_g;
    ev = (ev >= 0.f) ? ev : 0.2f * ev;
    float p = __expf(ev - m_g);
    asum += p;
    const float* fs = feat + (size_t)s * 512 + l * 8;
    f32x4 f0 = *(const f32x4*)fs;
    f32x4 f1 = *(const f32x4*)(fs + 4);
    acc[0] += p * f0[0]; acc[1] += p * f0[1]; acc[2] += p * f0[2]; acc[3] += p * f0[3];
    acc[4] += p * f1[0]; acc[5] += p * f1[1]; acc[6] += p * f1[2]; acc[7] += p * f1[3];
  }
  float inv = (end > beg) ? 1.f / asum : 1.f;
  const float* hr = hres + (size_t)wid * 512 + l * 8;
  float o[8];
#pragma unroll
  for (int j = 0; j < 8; ++j) o[j] = acc[j] * inv + hr[j];
  if constexpr (!FINAL) {
    u16x8 ob;
#pragma unroll
    for (int j = 0; j < 8; ++j) ob[j] = f2bf(fmaxf(o[j], 0.f));
    *(u16x8*)(hnext + (size_t)wid * 512 + l * 8) = ob;
  } else {
#pragma unroll
    for (int j = 0; j < 8; ++j) {
      float v = o[j];
      v += __shfl_xor(v, 16);
      v += __shfl_xor(v, 32);
      o[j] = v * 0.25f;
    }
    if (g == 0) {
      f32x4 o0 = (f32x4){o[0], o[1], o[2], o[3]};
      f32x4 o1 = (f32x4){o[4], o[5], o[6], o[7]};
      *(f32x4*)(h3 + (size_t)wid * 128 + (l & 15) * 8) = o0;
      *(f32x4*)(h3 + (size_t)wid * 128 + (l & 15) * 8 + 4) = o1;
    }
  }
}

// ---------------- fused groups_score: |h3[src]-h3[dst]| -> MLP -> sigmoid ----------------
__global__ __launch_bounds__(256) void k_groups(
    const float* __restrict__ h3, const int* __restrict__ src, const int* __restrict__ dst,
    const float* __restrict__ Wg1, const float* __restrict__ bg1,
    const float* __restrict__ Wg2, const float* __restrict__ bg2,
    float* __restrict__ out) {
  __shared__ __align__(16) unsigned short Xs[128 * 128];
  __shared__ __align__(16) unsigned short Ws[128 * 128];
  const int t = threadIdx.x;
  const int l = t & 63, w = t >> 6, wr = w >> 1, wc = w & 1;
  const int e0 = blockIdx.x * 128;
  {
    int r = t >> 1, hf = t & 1;
    int e = e0 + r;
    const float* pa = h3 + (size_t)src[e] * 128 + hf * 64;
    const float* pb = h3 + (size_t)dst[e] * 128 + hf * 64;
    const float* pw = Wg1 + (size_t)r * 128 + hf * 64;
#pragma unroll
    for (int c = 0; c < 64; c += 8) {
      f32x4 a0 = *(const f32x4*)(pa + c), a1 = *(const f32x4*)(pa + c + 4);
      f32x4 b0 = *(const f32x4*)(pb + c), b1 = *(const f32x4*)(pb + c + 4);
      f32x4 w0 = *(const f32x4*)(pw + c), w1 = *(const f32x4*)(pw + c + 4);
      u16x8 xv, wv;
#pragma unroll
      for (int j = 0; j < 4; ++j) {
        xv[j] = f2bf(fabsf(a0[j] - b0[j]));
        xv[j + 4] = f2bf(fabsf(a1[j] - b1[j]));
        wv[j] = f2bf(w0[j]);
        wv[j + 4] = f2bf(w1[j]);
      }
      int gb = hf * 8 + (c >> 3);
      *(u16x8*)&Xs[r * 128 + (gb ^ (r & 15)) * 8] = xv;
      *(u16x8*)&Ws[r * 128 + (gb ^ (r & 15)) * 8] = wv;
    }
  }
  __syncthreads();
  f32x4 acc[4][4];
#pragma unroll
  for (int m = 0; m < 4; ++m)
#pragma unroll
    for (int n = 0; n < 4; ++n) acc[m][n] = (f32x4){0.f, 0.f, 0.f, 0.f};
#pragma unroll
  for (int kk = 0; kk < 4; ++kk) {
    bf16x8 af[4], bfr[4];
#pragma unroll
    for (int m = 0; m < 4; ++m) {
      int row = wr * 64 + m * 16 + (l & 15);
      int gsw = (kk * 4 + (l >> 4)) ^ (row & 15);
      af[m] = *(const bf16x8*)&Xs[row * 128 + gsw * 8];
    }
#pragma unroll
    for (int n = 0; n < 4; ++n) {
      int row = wc * 64 + n * 16 + (l & 15);
      int gsw = (kk * 4 + (l >> 4)) ^ (row & 15);
      bfr[n] = *(const bf16x8*)&Ws[row * 128 + gsw * 8];
    }
#pragma unroll
    for (int m = 0; m < 4; ++m)
#pragma unroll
      for (int n = 0; n < 4; ++n)
        acc[m][n] = __builtin_amdgcn_mfma_f32_16x16x32_bf16(af[m], bfr[n], acc[m][n], 0, 0, 0);
  }
  float part[4][4];
#pragma unroll
  for (int m = 0; m < 4; ++m)
#pragma unroll
    for (int r = 0; r < 4; ++r) part[m][r] = 0.f;
#pragma unroll
  for (int n = 0; n < 4; ++n) {
    int col = wc * 64 + n * 16 + (l & 15);
    float b1 = bg1[col], w2 = Wg2[col];
#pragma unroll
    for (int m = 0; m < 4; ++m)
#pragma unroll
      for (int r = 0; r < 4; ++r) {
        float y = fmaxf(acc[m][n][r] + b1, 0.f);
        part[m][r] += y * w2;
      }
  }
#pragma unroll
  for (int d = 1; d < 16; d <<= 1)
#pragma unroll
    for (int m = 0; m < 4; ++m)
#pragma unroll
      for (int r = 0; r < 4; ++r) part[m][r] += __shfl_xor(part[m][r], d);
  __syncthreads();  // safe to alias Xs now
  float* sc = (float*)Xs;
  if ((l & 15) == 0) {
#pragma unroll
    for (int m = 0; m < 4; ++m)
#pragma unroll
      for (int r = 0; r < 4; ++r)
        sc[wc * 128 + wr * 64 + m * 16 + (l >> 4) * 4 + r] = part[m][r];
  }
  __syncthreads();
  if (t < 128) {
    float logit = sc[t] + sc[128 + t] + bg2[0];
    out[e0 + t] = sigmoidf(logit);
  }
}

// ---------------- entity segment sums ----------------
__global__ void k_ent_scatter(const float* __restrict__ h3, const float* __restrict__ pos,
                              const int* __restrict__ entity, float* __restrict__ ent_sum,
                              float* __restrict__ pos_sum, float* __restrict__ cnt) {
  int i = blockIdx.x * blockDim.x + threadIdx.x;
  if (i >= N_NODES * 32) return;
  int n = i >> 5, c = i & 31;
  int e = entity[n];
  f32x4 v = *(const f32x4*)(h3 + (size_t)n * 128 + c * 4);
  atomicAdd(&ent_sum[e * 128 + c * 4 + 0], v[0]);
  atomicAdd(&ent_sum[e * 128 + c * 4 + 1], v[1]);
  atomicAdd(&ent_sum[e * 128 + c * 4 + 2], v[2]);
  atomicAdd(&ent_sum[e * 128 + c * 4 + 3], v[3]);
  if (c == 0) {
    atomicAdd(&pos_sum[e * 2 + 0], pos[n * 2 + 0]);
    atomicAdd(&pos_sum[e * 2 + 1], pos[n * 2 + 1]);
    atomicAdd(&cnt[e], 1.f);
  }
}

__global__ void k_entity_states(const float* __restrict__ ent_sum, const float* __restrict__ We,
                                const float* __restrict__ be, float* __restrict__ es) {
  int i = blockIdx.x * blockDim.x + threadIdx.x;
  if (i >= NENT * 128) return;
  int e = i >> 7, j = i & 127;
  const float* x = ent_sum + (size_t)e * 128;
  const float* wrow = We + (size_t)j * 128;
  float s = be[j];
  for (int k = 0; k < 128; k += 4) {
    f32x4 xv = *(const f32x4*)(x + k);
    f32x4 wv = *(const f32x4*)(wrow + k);
    s += xv[0] * wv[0] + xv[1] * wv[1] + xv[2] * wv[2] + xv[3] * wv[3];
  }
  es[i] = s;
}

__global__ void k_entity_class(const float* __restrict__ es, const float* __restrict__ Wc,
                               const float* __restrict__ bc, float* __restrict__ out) {
  int i = blockIdx.x * blockDim.x + threadIdx.x;
  if (i >= NENT * 4) return;
  int e = i >> 2, c = i & 3;
  const float* x = es + (size_t)e * 128;
  const float* wrow = Wc + (size_t)c * 128;
  float s = bc[c];
  for (int k = 0; k < 128; ++k) s += x[k] * wrow[k];
  out[i] = sigmoidf(s);
}

__global__ void k_entity_pos(const float* __restrict__ pos_sum, const float* __restrict__ cnt,
                             float* __restrict__ outpos, float* __restrict__ wspos) {
  int e = blockIdx.x * blockDim.x + threadIdx.x;
  if (e >= NENT) return;
  float c = fmaxf(cnt[e], 1.f);
  float x = pos_sum[e * 2] / c, y = pos_sum[e * 2 + 1] / c;
  outpos[e * 2] = x; outpos[e * 2 + 1] = y;
  wspos[e * 2] = x; wspos[e * 2 + 1] = y;
}

// ---------------- exact knn (K smallest d2, ties -> smaller index) ----------------
__global__ __launch_bounds__(256) void k_knn(const float* __restrict__ entpos,
                                             int* __restrict__ knn) {
  __shared__ float d2row[NENT];
  __shared__ float rv[256];
  __shared__ int ri[256];
  int i = blockIdx.x, t = threadIdx.x;
  float px = entpos[i * 2], py = entpos[i * 2 + 1];
  for (int j = t; j < NENT; j += 256) {
    float dx = px - entpos[j * 2], dy = py - entpos[j * 2 + 1];
    d2row[j] = __fadd_rn(__fmul_rn(dx, dx), __fmul_rn(dy, dy));
  }
  __syncthreads();
  for (int k = 0; k < KNN_K; ++k) {
    float bv = __builtin_inff(); int bi = 0x7fffffff;
    for (int j = t; j < NENT; j += 256) {
      float v = d2row[j];
      if (v < bv) { bv = v; bi = j; }
    }
    rv[t] = bv; ri[t] = bi;
    __syncthreads();
    for (int s = 128; s > 0; s >>= 1) {
      if (t < s) {
        if (rv[t + s] < rv[t] || (rv[t + s] == rv[t] && ri[t + s] < ri[t])) {
          rv[t] = rv[t + s]; ri[t] = ri[t + s];
        }
      }
      __syncthreads();
    }
    if (t == 0) { knn[i * KNN_K + k] = ri[0]; d2row[ri[0]] = __builtin_inff(); }
    __syncthreads();
  }
}

// ---------------- link MLP (wave per pair) ----------------
__global__ void k_link(const float* __restrict__ es, const int* __restrict__ knn,
                       const float* __restrict__ Wl1, const float* __restrict__ bl1,
                       const float* __restrict__ Wl2, const float* __restrict__ bl2,
                       float* __restrict__ out) {
  int wid = (blockIdx.x * blockDim.x + threadIdx.x) >> 6;
  if (wid >= NENT * KNN_K) return;
  int l = threadIdx.x & 63;
  int de = wid / KNN_K;
  int se = knn[wid];
  float x0 = fabsf(es[(size_t)se * 128 + 2 * l] - es[(size_t)de * 128 + 2 * l]);
  float x1 = fabsf(es[(size_t)se * 128 + 2 * l + 1] - es[(size_t)de * 128 + 2 * l + 1]);
  float yl = bl1[l], yh = bl1[l + 64];
  for (int k = 0; k < 128; ++k) {
    float pick = (k & 1) ? x1 : x0;
    float xv = __shfl(pick, k >> 1);
    yl += Wl1[(size_t)l * 128 + k] * xv;
    yh += Wl1[(size_t)(l + 64) * 128 + k] * xv;
  }
  float s = fmaxf(yl, 0.f) * Wl2[l] + fmaxf(yh, 0.f) * Wl2[l + 64];
#pragma unroll
  for (int d = 1; d < 64; d <<= 1) s += __shfl_xor(s, d);
  if (l == 0) out[wid] = sigmoidf(s + bl2[0]);
}

// =======================================================================
extern "C" void kernel_launch(void* const* d_in, const int* in_sizes, int n_in,
                              void* d_out, int out_size, void* d_ws, size_t ws_size,
                              hipStream_t stream) {
  const float* position = (const float*)d_in[0];
  const float* w_embed  = (const float*)d_in[1];
  const int*   src      = (const int*)d_in[2];
  const int*   dst      = (const int*)d_in[3];
  const int*   entity   = (const int*)d_in[4];
  const float* W1 = (const float*)d_in[5];
  const float* al1 = (const float*)d_in[6];
  const float* ar1 = (const float*)d_in[7];
  const float* Wr1 = (const float*)d_in[8];
  const float* W2 = (const float*)d_in[9];
  const float* al2 = (const float*)d_in[10];
  const float* ar2 = (const float*)d_in[11];
  const float* Wr2 = (const float*)d_in[12];
  const float* W3 = (const float*)d_in[13];
  const float* al3 = (const float*)d_in[14];
  const float* ar3 = (const float*)d_in[15];
  const float* Wr3 = (const float*)d_in[16];
  const float* Wg1 = (const float*)d_in[17];
  const float* bg1 = (const float*)d_in[18];
  const float* Wg2 = (const float*)d_in[19];
  const float* bg2 = (const float*)d_in[20];
  const float* We  = (const float*)d_in[21];
  const float* be  = (const float*)d_in[22];
  const float* Wl1 = (const float*)d_in[23];
  const float* bl1 = (const float*)d_in[24];
  const float* Wl2 = (const float*)d_in[25];
  const float* bl2 = (const float*)d_in[26];
  const float* Wc  = (const float*)d_in[27];
  const float* bc  = (const float*)d_in[28];

  float* out_groups = (float*)d_out;
  float* out_class  = out_groups + N_EDGES;
  float* out_pos    = out_class + NENT * 4;
  float* out_link   = out_pos + NENT * 2;

  char* ws = (char*)d_ws;
  size_t off = 0;
  auto carve = [&](size_t bytes) -> char* {
    char* p = ws + off;
    off = (off + bytes + 255) & ~(size_t)255;
    return p;
  };
  float* feat = (float*)carve((size_t)N_NODES * 512 * 4);
  float* hres = (float*)carve((size_t)N_NODES * 512 * 4);
  unsigned short* hA = (unsigned short*)carve((size_t)N_NODES * 512 * 2);
  unsigned short* hB = (unsigned short*)carve((size_t)N_NODES * 512 * 2);
  unsigned short* wbf = (unsigned short*)carve(512 * 512 * 2);
  unsigned short* wrbf = (unsigned short*)carve(512 * 512 * 2);
  float* el = (float*)carve((size_t)N_NODES * 4 * 4);
  float* er = (float*)carve((size_t)N_NODES * 4 * 4);
  int* indeg = (int*)carve((size_t)N_NODES * 4);
  int* indptr = (int*)carve((size_t)(N_NODES + 1) * 4);
  int* cursor = (int*)carve((size_t)N_NODES * 4);
  int* csr_src = (int*)carve((size_t)N_EDGES * 4);
  float* h3 = (float*)carve((size_t)N_NODES * 128 * 4);
  float* ent_sum = (float*)carve((size_t)NENT * 128 * 4);
  float* pos_sum = (float*)carve((size_t)NENT * 2 * 4);
  float* cnt = (float*)carve((size_t)NENT * 4);
  float* es = (float*)carve((size_t)NENT * 128 * 4);
  float* wspos = (float*)carve((size_t)NENT * 2 * 4);
  int* knn = (int*)carve((size_t)NENT * KNN_K * 4);

  // ---- CSR over dst (shared by all 3 GAT layers) ----
  hipMemsetAsync(indeg, 0, (size_t)N_NODES * 4, stream);
  k_hist<<<(N_EDGES + 255) / 256, 256, 0, stream>>>(dst, indeg);
  k_scan_fast<<<1, 1024, 0, stream>>>(indeg, indptr, cursor);
  k_scatter<<<(N_EDGES + 255) / 256, 256, 0, stream>>>(src, dst, cursor, csr_src);

  k_build_h0<<<(N_NODES * 128 + 255) / 256, 256, 0, stream>>>(position, w_embed, hA);

  dim3 ggrid((N_NODES + 127) / 128, 4), gblk(256);

  // ---- layer 1 (K=128) ----
  k_f2bf<<<(512 * 128 / 4 + 255) / 256, 256, 0, stream>>>(W1, wbf, 512 * 128);
  k_f2bf<<<(512 * 128 / 4 + 255) / 256, 256, 0, stream>>>(Wr1, wrbf, 512 * 128);
  k_gemm_bt<<<ggrid, gblk, 0, stream>>>(hA, wbf, feat, N_NODES, 512, 128);
  k_gemm_bt<<<ggrid, gblk, 0, stream>>>(hA, wrbf, hres, N_NODES, 512, 128);
  k_el_er<<<5000, 256, 0, stream>>>(feat, al1, ar1, el, er);
  k_gat_agg<false><<<5000, 256, 0, stream>>>(feat, hres, el, er, indptr, csr_src, hB, nullptr);

  // ---- layer 2 (K=512) ----
  k_f2bf<<<(512 * 512 / 4 + 255) / 256, 256, 0, stream>>>(W2, wbf, 512 * 512);
  k_f2bf<<<(512 * 512 / 4 + 255) / 256, 256, 0, stream>>>(Wr2, wrbf, 512 * 512);
  k_gemm_bt<<<ggrid, gblk, 0, stream>>>(hB, wbf, feat, N_NODES, 512, 512);
  k_gemm_bt<<<ggrid, gblk, 0, stream>>>(hB, wrbf, hres, N_NODES, 512, 512);
  k_el_er<<<5000, 256, 0, stream>>>(feat, al2, ar2, el, er);
  k_gat_agg<false><<<5000, 256, 0, stream>>>(feat, hres, el, er, indptr, csr_src, hA, nullptr);

  // ---- layer 3 (K=512, no relu, head-mean) ----
  k_f2bf<<<(512 * 512 / 4 + 255) / 256, 256, 0, stream>>>(W3, wbf, 512 * 512);
  k_f2bf<<<(512 * 512 / 4 + 255) / 256, 256, 0, stream>>>(Wr3, wrbf, 512 * 512);
  k_gemm_bt<<<ggrid, gblk, 0, stream>>>(hA, wbf, feat, N_NODES, 512, 512);
  k_gemm_bt<<<ggrid, gblk, 0, stream>>>(hA, wrbf, hres, N_NODES, 512, 512);
  k_el_er<<<5000, 256, 0, stream>>>(feat, al3, ar3, el, er);
  k_gat_agg<true><<<5000, 256, 0, stream>>>(feat, hres, el, er, indptr, csr_src, nullptr, h3);

  // ---- groups_score (fused) ----
  k_groups<<<N_EDGES / 128, 256, 0, stream>>>(h3, src, dst, Wg1, bg1, Wg2, bg2, out_groups);

  // ---- entity path ----
  hipMemsetAsync(ent_sum, 0, (size_t)NENT * 128 * 4, stream);
  hipMemsetAsync(pos_sum, 0, (size_t)NENT * 2 * 4, stream);
  hipMemsetAsync(cnt, 0, (size_t)NENT * 4, stream);
  k_ent_scatter<<<(N_NODES * 32 + 255) / 256, 256, 0, stream>>>(h3, position, entity, ent_sum,
                                                                pos_sum, cnt);
  k_entity_states<<<(NENT * 128 + 255) / 256, 256, 0, stream>>>(ent_sum, We, be, es);
  k_entity_class<<<(NENT * 4 + 255) / 256, 256, 0, stream>>>(es, Wc, bc, out_class);
  k_entity_pos<<<(NENT + 255) / 256, 256, 0, stream>>>(pos_sum, cnt, out_pos, wspos);
  k_knn<<<NENT, 256, 0, stream>>>(wspos, knn);
  k_link<<<(NENT * KNN_K * 64 + 255) / 256, 256, 0, stream>>>(es, knn, Wl1, bl1, Wl2, bl2,
                                                              out_link);
}

// Round 3
// 708.799 us; speedup vs baseline: 1.3691x; 1.1906x over previous
//
#include <hip/hip_runtime.h>
#include <math.h>

#define N_NODES 20000
#define N_EDGES 320000
#define NENT    2000
#define KNN_K   10

typedef __attribute__((ext_vector_type(4))) float f32x4;
typedef __attribute__((ext_vector_type(8))) short bf16x8;
typedef __attribute__((ext_vector_type(8))) unsigned short u16x8;
typedef __attribute__((ext_vector_type(4))) unsigned short u16x4;

__device__ __forceinline__ unsigned short f2bf(float f) {
  union { float f; unsigned u; } v; v.f = f;
  unsigned r = v.u + 0x7fffu + ((v.u >> 16) & 1u);
  return (unsigned short)(r >> 16);
}
__device__ __forceinline__ float sigmoidf(float x) {
  return 1.f / (1.f + __expf(-x));
}

// ---------------- h0 = concat(position, w_embed) -> bf16 ----------------
__global__ void k_build_h0(const float* __restrict__ pos, const float* __restrict__ wemb,
                           unsigned short* __restrict__ h0) {
  int i = blockIdx.x * blockDim.x + threadIdx.x;
  if (i >= N_NODES * 128) return;
  int n = i >> 7, c = i & 127;
  float v = (c < 2) ? pos[n * 2 + c] : wemb[n * 126 + (c - 2)];
  h0[i] = f2bf(v);
}

// ---------------- generic f32 -> bf16 (n multiple of 4) ----------------
__global__ void k_f2bf(const float* __restrict__ in, unsigned short* __restrict__ out, int n) {
  int i = blockIdx.x * blockDim.x + threadIdx.x;
  if (i * 4 >= n) return;
  f32x4 v = *(const f32x4*)(in + i * 4);
  u16x4 o;
  o[0] = f2bf(v[0]); o[1] = f2bf(v[1]); o[2] = f2bf(v[2]); o[3] = f2bf(v[3]);
  *(u16x4*)(out + i * 4) = o;
}

// ---------------- bf16 MFMA GEMM: C[M,Nn] = A[M,K] * B[Nn,K]^T ----------------
__global__ __launch_bounds__(256) void k_gemm_bt(
    const unsigned short* __restrict__ A, const unsigned short* __restrict__ B,
    float* __restrict__ C, int M, int Nn, int K) {
  __shared__ __align__(16) unsigned short As[128 * 64];
  __shared__ __align__(16) unsigned short Bs[128 * 64];
  const int bm = blockIdx.x * 128, bn = blockIdx.y * 128;
  const int t = threadIdx.x;
  const int l = t & 63, w = t >> 6;
  const int wr = w >> 1, wc = w & 1;
  f32x4 acc[4][4];
#pragma unroll
  for (int m = 0; m < 4; ++m)
#pragma unroll
    for (int n = 0; n < 4; ++n) acc[m][n] = (f32x4){0.f, 0.f, 0.f, 0.f};

  for (int kb = 0; kb < K; kb += 64) {
    __syncthreads();
#pragma unroll
    for (int i = 0; i < 4; ++i) {
      int c = t + 256 * i;         // 1024 16B-chunks per tile
      int row = c >> 3, cc = c & 7;
      int sw = cc ^ (row & 7);     // T2 xor-swizzle (granule)
      int ar = bm + row; if (ar > M - 1) ar = M - 1;
      *(f32x4*)&As[row * 64 + sw * 8] = *(const f32x4*)(A + (size_t)ar * K + kb + cc * 8);
      *(f32x4*)&Bs[row * 64 + sw * 8] = *(const f32x4*)(B + (size_t)(bn + row) * K + kb + cc * 8);
    }
    __syncthreads();
#pragma unroll
    for (int kk = 0; kk < 2; ++kk) {
      bf16x8 af[4], bfr[4];
#pragma unroll
      for (int m = 0; m < 4; ++m) {
        int row = wr * 64 + m * 16 + (l & 15);
        int g = (kk * 4 + (l >> 4)) ^ (row & 7);
        af[m] = *(const bf16x8*)&As[row * 64 + g * 8];
      }
#pragma unroll
      for (int n = 0; n < 4; ++n) {
        int row = wc * 64 + n * 16 + (l & 15);
        int g = (kk * 4 + (l >> 4)) ^ (row & 7);
        bfr[n] = *(const bf16x8*)&Bs[row * 64 + g * 8];
      }
#pragma unroll
      for (int m = 0; m < 4; ++m)
#pragma unroll
        for (int n = 0; n < 4; ++n)
          acc[m][n] = __builtin_amdgcn_mfma_f32_16x16x32_bf16(af[m], bfr[n], acc[m][n], 0, 0, 0);
    }
  }
#pragma unroll
  for (int m = 0; m < 4; ++m) {
    int r0 = bm + wr * 64 + m * 16 + ((l >> 4) << 2);
#pragma unroll
    for (int n = 0; n < 4; ++n) {
      int c0 = bn + wc * 64 + n * 16 + (l & 15);
#pragma unroll
      for (int r = 0; r < 4; ++r) {
        int row = r0 + r;
        if (row < M) C[(size_t)row * Nn + c0] = acc[m][n][r];
      }
    }
  }
}

// ---------------- el/er: per (node, head) dot(feat, al/ar) ----------------
__global__ void k_el_er(const float* __restrict__ feat, const float* __restrict__ al,
                        const float* __restrict__ ar, float* __restrict__ el,
                        float* __restrict__ er) {
  int wid = (blockIdx.x * blockDim.x + threadIdx.x) >> 6;
  if (wid >= N_NODES) return;
  int l = threadIdx.x & 63;
  int g = l >> 4, q = l & 15;
  const float* fr = feat + (size_t)wid * 512 + l * 8;
  const float* alp = al + g * 128 + q * 8;
  const float* arp = ar + g * 128 + q * 8;
  float sl = 0.f, sr = 0.f;
#pragma unroll
  for (int j = 0; j < 8; ++j) { float f = fr[j]; sl += f * alp[j]; sr += f * arp[j]; }
#pragma unroll
  for (int d = 1; d < 16; d <<= 1) { sl += __shfl_xor(sl, d); sr += __shfl_xor(sr, d); }
  if (q == 0) { el[wid * 4 + g] = sl; er[wid * 4 + g] = sr; }
}

// ---------------- CSR build ----------------
__global__ void k_hist(const int* __restrict__ dst, int* __restrict__ indeg) {
  int e = blockIdx.x * blockDim.x + threadIdx.x;
  if (e < N_EDGES) atomicAdd(&indeg[dst[e]], 1);
}

// single-block 1024-thread scan: indptr + cursor init
__global__ __launch_bounds__(1024) void k_scan_fast(const int* __restrict__ indeg,
                                                    int* __restrict__ indptr,
                                                    int* __restrict__ cursor) {
  __shared__ int wsum[16];
  const int t = threadIdx.x;
  const int l = t & 63, w = t >> 6;
  const int CH = 20;  // 1024*20 >= 20000
  int base = t * CH;
  int vals[CH];
  int s = 0;
#pragma unroll
  for (int i = 0; i < CH; ++i) {
    int idx = base + i;
    int v = (idx < N_NODES) ? indeg[idx] : 0;
    vals[i] = v;
    s += v;
  }
  int ss = s;
#pragma unroll
  for (int d = 1; d < 64; d <<= 1) { int o = __shfl_up(ss, d); if (l >= d) ss += o; }
  if (l == 63) wsum[w] = ss;
  __syncthreads();
  if (t < 16) {
    int v = wsum[t];
#pragma unroll
    for (int d = 1; d < 16; d <<= 1) { int o = __shfl_up(v, d); if (t >= d) v += o; }
    wsum[t] = v;
  }
  __syncthreads();
  int run = ((w > 0) ? wsum[w - 1] : 0) + ss - s;  // exclusive prefix of this thread
  if (t == 0) indptr[0] = 0;
#pragma unroll
  for (int i = 0; i < CH; ++i) {
    int idx = base + i;
    if (idx < N_NODES) {
      cursor[idx] = run;
      run += vals[i];
      indptr[idx + 1] = run;
    }
  }
}

__global__ void k_scatter(const int* __restrict__ src, const int* __restrict__ dst,
                          int* __restrict__ cursor, int* __restrict__ csr_src) {
  int e = blockIdx.x * blockDim.x + threadIdx.x;
  if (e < N_EDGES) {
    int p = atomicAdd(&cursor[dst[e]], 1);
    csr_src[p] = src[e];
  }
}

// ---------------- GAT edge-softmax + aggregation (wave per dst node) ----------------
template <bool FINAL>
__global__ void k_gat_agg(const float* __restrict__ feat, const float* __restrict__ hres,
                          const float* __restrict__ el, const float* __restrict__ er,
                          const int* __restrict__ indptr, const int* __restrict__ csr_src,
                          unsigned short* __restrict__ hnext, float* __restrict__ h3) {
  int wid = (blockIdx.x * blockDim.x + threadIdx.x) >> 6;
  if (wid >= N_NODES) return;
  int l = threadIdx.x & 63;
  int g = l >> 4;
  int beg = indptr[wid], end = indptr[wid + 1];
  f32x4 er4 = *(const f32x4*)(er + wid * 4);
  const float NI = -__builtin_inff();
  f32x4 mx = (f32x4){NI, NI, NI, NI};
  for (int j = beg + l; j < end; j += 64) {
    int s = csr_src[j];
    f32x4 el4 = *(const f32x4*)(el + s * 4);
#pragma unroll
    for (int h = 0; h < 4; ++h) {
      float v = el4[h] + er4[h];
      v = (v >= 0.f) ? v : 0.2f * v;
      mx[h] = fmaxf(mx[h], v);
    }
  }
#pragma unroll
  for (int d = 1; d < 64; d <<= 1) {
#pragma unroll
    for (int h = 0; h < 4; ++h) mx[h] = fmaxf(mx[h], __shfl_xor(mx[h], d));
  }
  float m_g = mx[g];
  float er_g = er4[g];
  float asum = 0.f;
  float acc[8];
#pragma unroll
  for (int j = 0; j < 8; ++j) acc[j] = 0.f;
  for (int j = beg; j < end; ++j) {
    int s = csr_src[j];
    float ev = el[s * 4 + g] + er_g;
    ev = (ev >= 0.f) ? ev : 0.2f * ev;
    float p = __expf(ev - m_g);
    asum += p;
    const float* fs = feat + (size_t)s * 512 + l * 8;
    f32x4 f0 = *(const f32x4*)fs;
    f32x4 f1 = *(const f32x4*)(fs + 4);
    acc[0] += p * f0[0]; acc[1] += p * f0[1]; acc[2] += p * f0[2]; acc[3] += p * f0[3];
    acc[4] += p * f1[0]; acc[5] += p * f1[1]; acc[6] += p * f1[2]; acc[7] += p * f1[3];
  }
  float inv = (end > beg) ? 1.f / asum : 1.f;
  const float* hr = hres + (size_t)wid * 512 + l * 8;
  float o[8];
#pragma unroll
  for (int j = 0; j < 8; ++j) o[j] = acc[j] * inv + hr[j];
  if constexpr (!FINAL) {
    u16x8 ob;
#pragma unroll
    for (int j = 0; j < 8; ++j) ob[j] = f2bf(fmaxf(o[j], 0.f));
    *(u16x8*)(hnext + (size_t)wid * 512 + l * 8) = ob;
  } else {
#pragma unroll
    for (int j = 0; j < 8; ++j) {
      float v = o[j];
      v += __shfl_xor(v, 16);
      v += __shfl_xor(v, 32);
      o[j] = v * 0.25f;
    }
    if (g == 0) {
      f32x4 o0 = (f32x4){o[0], o[1], o[2], o[3]};
      f32x4 o1 = (f32x4){o[4], o[5], o[6], o[7]};
      *(f32x4*)(h3 + (size_t)wid * 128 + (l & 15) * 8) = o0;
      *(f32x4*)(h3 + (size_t)wid * 128 + (l & 15) * 8 + 4) = o1;
    }
  }
}

// ---- fused pair MLP: sigmoid(relu(|X[a]-X[b]| @ W1^T + b1) @ W2^T + b2) ----
// MODE 0: a=ia[e], b=ib[e] (groups_score, npairs multiple of 128)
// MODE 1: a=ia[e] (knn flat), b=e/KNN_K (entity_link_score, tail-guarded)
template <int MODE>
__global__ __launch_bounds__(256) void k_pair_mlp(
    const float* __restrict__ X, const int* __restrict__ ia, const int* __restrict__ ib,
    const float* __restrict__ W1, const float* __restrict__ b1,
    const float* __restrict__ W2, const float* __restrict__ b2,
    float* __restrict__ out, int npairs) {
  __shared__ __align__(16) unsigned short Xs[128 * 128];
  __shared__ __align__(16) unsigned short Ws[128 * 128];
  const int t = threadIdx.x;
  const int l = t & 63, w = t >> 6, wr = w >> 1, wc = w & 1;
  const int e0 = blockIdx.x * 128;
  {
    int r = t >> 1, hf = t & 1;
    int e = e0 + r;
    if (MODE == 1 && e >= npairs) e = npairs - 1;
    int sa, sb;
    if (MODE == 0) { sa = ia[e]; sb = ib[e]; }
    else           { sa = ia[e]; sb = e / KNN_K; }
    const float* pa = X + (size_t)sa * 128 + hf * 64;
    const float* pb = X + (size_t)sb * 128 + hf * 64;
    const float* pw = W1 + (size_t)r * 128 + hf * 64;
#pragma unroll
    for (int c = 0; c < 64; c += 8) {
      f32x4 a0 = *(const f32x4*)(pa + c), a1 = *(const f32x4*)(pa + c + 4);
      f32x4 b0 = *(const f32x4*)(pb + c), b1v = *(const f32x4*)(pb + c + 4);
      f32x4 w0 = *(const f32x4*)(pw + c), w1 = *(const f32x4*)(pw + c + 4);
      u16x8 xv, wv;
#pragma unroll
      for (int j = 0; j < 4; ++j) {
        xv[j] = f2bf(fabsf(a0[j] - b0[j]));
        xv[j + 4] = f2bf(fabsf(a1[j] - b1v[j]));
        wv[j] = f2bf(w0[j]);
        wv[j + 4] = f2bf(w1[j]);
      }
      int gb = hf * 8 + (c >> 3);
      *(u16x8*)&Xs[r * 128 + (gb ^ (r & 15)) * 8] = xv;
      *(u16x8*)&Ws[r * 128 + (gb ^ (r & 15)) * 8] = wv;
    }
  }
  __syncthreads();
  f32x4 acc[4][4];
#pragma unroll
  for (int m = 0; m < 4; ++m)
#pragma unroll
    for (int n = 0; n < 4; ++n) acc[m][n] = (f32x4){0.f, 0.f, 0.f, 0.f};
#pragma unroll
  for (int kk = 0; kk < 4; ++kk) {
    bf16x8 af[4], bfr[4];
#pragma unroll
    for (int m = 0; m < 4; ++m) {
      int row = wr * 64 + m * 16 + (l & 15);
      int gsw = (kk * 4 + (l >> 4)) ^ (row & 15);
      af[m] = *(const bf16x8*)&Xs[row * 128 + gsw * 8];
    }
#pragma unroll
    for (int n = 0; n < 4; ++n) {
      int row = wc * 64 + n * 16 + (l & 15);
      int gsw = (kk * 4 + (l >> 4)) ^ (row & 15);
      bfr[n] = *(const bf16x8*)&Ws[row * 128 + gsw * 8];
    }
#pragma unroll
    for (int m = 0; m < 4; ++m)
#pragma unroll
      for (int n = 0; n < 4; ++n)
        acc[m][n] = __builtin_amdgcn_mfma_f32_16x16x32_bf16(af[m], bfr[n], acc[m][n], 0, 0, 0);
  }
  float part[4][4];
#pragma unroll
  for (int m = 0; m < 4; ++m)
#pragma unroll
    for (int r = 0; r < 4; ++r) part[m][r] = 0.f;
#pragma unroll
  for (int n = 0; n < 4; ++n) {
    int col = wc * 64 + n * 16 + (l & 15);
    float bb = b1[col], w2 = W2[col];
#pragma unroll
    for (int m = 0; m < 4; ++m)
#pragma unroll
      for (int r = 0; r < 4; ++r) {
        float y = fmaxf(acc[m][n][r] + bb, 0.f);
        part[m][r] += y * w2;
      }
  }
#pragma unroll
  for (int d = 1; d < 16; d <<= 1)
#pragma unroll
    for (int m = 0; m < 4; ++m)
#pragma unroll
      for (int r = 0; r < 4; ++r) part[m][r] += __shfl_xor(part[m][r], d);
  __syncthreads();  // safe to alias Xs now
  float* sc = (float*)Xs;
  if ((l & 15) == 0) {
#pragma unroll
    for (int m = 0; m < 4; ++m)
#pragma unroll
      for (int r = 0; r < 4; ++r)
        sc[wc * 128 + wr * 64 + m * 16 + (l >> 4) * 4 + r] = part[m][r];
  }
  __syncthreads();
  if (t < 128 && (MODE == 0 || e0 + t < npairs)) {
    float logit = sc[t] + sc[128 + t] + b2[0];
    out[e0 + t] = sigmoidf(logit);
  }
}

// ---------------- entity segment sums ----------------
__global__ void k_ent_scatter(const float* __restrict__ h3, const float* __restrict__ pos,
                              const int* __restrict__ entity, float* __restrict__ ent_sum,
                              float* __restrict__ pos_sum, float* __restrict__ cnt) {
  int i = blockIdx.x * blockDim.x + threadIdx.x;
  if (i >= N_NODES * 32) return;
  int n = i >> 5, c = i & 31;
  int e = entity[n];
  f32x4 v = *(const f32x4*)(h3 + (size_t)n * 128 + c * 4);
  atomicAdd(&ent_sum[e * 128 + c * 4 + 0], v[0]);
  atomicAdd(&ent_sum[e * 128 + c * 4 + 1], v[1]);
  atomicAdd(&ent_sum[e * 128 + c * 4 + 2], v[2]);
  atomicAdd(&ent_sum[e * 128 + c * 4 + 3], v[3]);
  if (c == 0) {
    atomicAdd(&pos_sum[e * 2 + 0], pos[n * 2 + 0]);
    atomicAdd(&pos_sum[e * 2 + 1], pos[n * 2 + 1]);
    atomicAdd(&cnt[e], 1.f);
  }
}

__global__ void k_entity_states(const float* __restrict__ ent_sum, const float* __restrict__ We,
                                const float* __restrict__ be, float* __restrict__ es) {
  int i = blockIdx.x * blockDim.x + threadIdx.x;
  if (i >= NENT * 128) return;
  int e = i >> 7, j = i & 127;
  const float* x = ent_sum + (size_t)e * 128;
  const float* wrow = We + (size_t)j * 128;
  float s = be[j];
  for (int k = 0; k < 128; k += 4) {
    f32x4 xv = *(const f32x4*)(x + k);
    f32x4 wv = *(const f32x4*)(wrow + k);
    s += xv[0] * wv[0] + xv[1] * wv[1] + xv[2] * wv[2] + xv[3] * wv[3];
  }
  es[i] = s;
}

__global__ void k_entity_class(const float* __restrict__ es, const float* __restrict__ Wc,
                               const float* __restrict__ bc, float* __restrict__ out) {
  int i = blockIdx.x * blockDim.x + threadIdx.x;
  if (i >= NENT * 4) return;
  int e = i >> 2, c = i & 3;
  const float* x = es + (size_t)e * 128;
  const float* wrow = Wc + (size_t)c * 128;
  float s = bc[c];
  for (int k = 0; k < 128; ++k) s += x[k] * wrow[k];
  out[i] = sigmoidf(s);
}

__global__ void k_entity_pos(const float* __restrict__ pos_sum, const float* __restrict__ cnt,
                             float* __restrict__ outpos, float* __restrict__ wspos) {
  int e = blockIdx.x * blockDim.x + threadIdx.x;
  if (e >= NENT) return;
  float c = fmaxf(cnt[e], 1.f);
  float x = pos_sum[e * 2] / c, y = pos_sum[e * 2 + 1] / c;
  outpos[e * 2] = x; outpos[e * 2 + 1] = y;
  wspos[e * 2] = x; wspos[e * 2 + 1] = y;
}

// ---------------- exact knn (K smallest d2, ties -> smaller index) ----------------
__global__ __launch_bounds__(256) void k_knn(const float* __restrict__ entpos,
                                             int* __restrict__ knn) {
  __shared__ float d2row[NENT];
  __shared__ float rv[256];
  __shared__ int ri[256];
  int i = blockIdx.x, t = threadIdx.x;
  float px = entpos[i * 2], py = entpos[i * 2 + 1];
  for (int j = t; j < NENT; j += 256) {
    float dx = px - entpos[j * 2], dy = py - entpos[j * 2 + 1];
    d2row[j] = __fadd_rn(__fmul_rn(dx, dx), __fmul_rn(dy, dy));
  }
  __syncthreads();
  for (int k = 0; k < KNN_K; ++k) {
    float bv = __builtin_inff(); int bi = 0x7fffffff;
    for (int j = t; j < NENT; j += 256) {
      float v = d2row[j];
      if (v < bv) { bv = v; bi = j; }
    }
    rv[t] = bv; ri[t] = bi;
    __syncthreads();
    for (int s = 128; s > 0; s >>= 1) {
      if (t < s) {
        if (rv[t + s] < rv[t] || (rv[t + s] == rv[t] && ri[t + s] < ri[t])) {
          rv[t] = rv[t + s]; ri[t] = ri[t + s];
        }
      }
      __syncthreads();
    }
    if (t == 0) { knn[i * KNN_K + k] = ri[0]; d2row[ri[0]] = __builtin_inff(); }
    __syncthreads();
  }
}

// =======================================================================
extern "C" void kernel_launch(void* const* d_in, const int* in_sizes, int n_in,
                              void* d_out, int out_size, void* d_ws, size_t ws_size,
                              hipStream_t stream) {
  const float* position = (const float*)d_in[0];
  const float* w_embed  = (const float*)d_in[1];
  const int*   src      = (const int*)d_in[2];
  const int*   dst      = (const int*)d_in[3];
  const int*   entity   = (const int*)d_in[4];
  const float* W1 = (const float*)d_in[5];
  const float* al1 = (const float*)d_in[6];
  const float* ar1 = (const float*)d_in[7];
  const float* Wr1 = (const float*)d_in[8];
  const float* W2 = (const float*)d_in[9];
  const float* al2 = (const float*)d_in[10];
  const float* ar2 = (const float*)d_in[11];
  const float* Wr2 = (const float*)d_in[12];
  const float* W3 = (const float*)d_in[13];
  const float* al3 = (const float*)d_in[14];
  const float* ar3 = (const float*)d_in[15];
  const float* Wr3 = (const float*)d_in[16];
  const float* Wg1 = (const float*)d_in[17];
  const float* bg1 = (const float*)d_in[18];
  const float* Wg2 = (const float*)d_in[19];
  const float* bg2 = (const float*)d_in[20];
  const float* We  = (const float*)d_in[21];
  const float* be  = (const float*)d_in[22];
  const float* Wl1 = (const float*)d_in[23];
  const float* bl1 = (const float*)d_in[24];
  const float* Wl2 = (const float*)d_in[25];
  const float* bl2 = (const float*)d_in[26];
  const float* Wc  = (const float*)d_in[27];
  const float* bc  = (const float*)d_in[28];

  float* out_groups = (float*)d_out;
  float* out_class  = out_groups + N_EDGES;
  float* out_pos    = out_class + NENT * 4;
  float* out_link   = out_pos + NENT * 2;

  char* ws = (char*)d_ws;
  size_t off = 0;
  auto carve = [&](size_t bytes) -> char* {
    char* p = ws + off;
    off = (off + bytes + 255) & ~(size_t)255;
    return p;
  };
  float* feat = (float*)carve((size_t)N_NODES * 512 * 4);
  float* hres = (float*)carve((size_t)N_NODES * 512 * 4);
  unsigned short* hA = (unsigned short*)carve((size_t)N_NODES * 512 * 2);
  unsigned short* hB = (unsigned short*)carve((size_t)N_NODES * 512 * 2);
  unsigned short* wbf = (unsigned short*)carve(512 * 512 * 2);
  unsigned short* wrbf = (unsigned short*)carve(512 * 512 * 2);
  float* el = (float*)carve((size_t)N_NODES * 4 * 4);
  float* er = (float*)carve((size_t)N_NODES * 4 * 4);
  int* indeg = (int*)carve((size_t)N_NODES * 4);
  int* indptr = (int*)carve((size_t)(N_NODES + 1) * 4);
  int* cursor = (int*)carve((size_t)N_NODES * 4);
  int* csr_src = (int*)carve((size_t)N_EDGES * 4);
  float* h3 = (float*)carve((size_t)N_NODES * 128 * 4);
  float* ent_sum = (float*)carve((size_t)NENT * 128 * 4);
  float* pos_sum = (float*)carve((size_t)NENT * 2 * 4);
  float* cnt = (float*)carve((size_t)NENT * 4);
  float* es = (float*)carve((size_t)NENT * 128 * 4);
  float* wspos = (float*)carve((size_t)NENT * 2 * 4);
  int* knn = (int*)carve((size_t)NENT * KNN_K * 4);

  // ---- CSR over dst (shared by all 3 GAT layers) ----
  hipMemsetAsync(indeg, 0, (size_t)N_NODES * 4, stream);
  k_hist<<<(N_EDGES + 255) / 256, 256, 0, stream>>>(dst, indeg);
  k_scan_fast<<<1, 1024, 0, stream>>>(indeg, indptr, cursor);
  k_scatter<<<(N_EDGES + 255) / 256, 256, 0, stream>>>(src, dst, cursor, csr_src);

  k_build_h0<<<(N_NODES * 128 + 255) / 256, 256, 0, stream>>>(position, w_embed, hA);

  dim3 ggrid((N_NODES + 127) / 128, 4), gblk(256);

  // ---- layer 1 (K=128) ----
  k_f2bf<<<(512 * 128 / 4 + 255) / 256, 256, 0, stream>>>(W1, wbf, 512 * 128);
  k_f2bf<<<(512 * 128 / 4 + 255) / 256, 256, 0, stream>>>(Wr1, wrbf, 512 * 128);
  k_gemm_bt<<<ggrid, gblk, 0, stream>>>(hA, wbf, feat, N_NODES, 512, 128);
  k_gemm_bt<<<ggrid, gblk, 0, stream>>>(hA, wrbf, hres, N_NODES, 512, 128);
  k_el_er<<<5000, 256, 0, stream>>>(feat, al1, ar1, el, er);
  k_gat_agg<false><<<5000, 256, 0, stream>>>(feat, hres, el, er, indptr, csr_src, hB, nullptr);

  // ---- layer 2 (K=512) ----
  k_f2bf<<<(512 * 512 / 4 + 255) / 256, 256, 0, stream>>>(W2, wbf, 512 * 512);
  k_f2bf<<<(512 * 512 / 4 + 255) / 256, 256, 0, stream>>>(Wr2, wrbf, 512 * 512);
  k_gemm_bt<<<ggrid, gblk, 0, stream>>>(hB, wbf, feat, N_NODES, 512, 512);
  k_gemm_bt<<<ggrid, gblk, 0, stream>>>(hB, wrbf, hres, N_NODES, 512, 512);
  k_el_er<<<5000, 256, 0, stream>>>(feat, al2, ar2, el, er);
  k_gat_agg<false><<<5000, 256, 0, stream>>>(feat, hres, el, er, indptr, csr_src, hA, nullptr);

  // ---- layer 3 (K=512, no relu, head-mean) ----
  k_f2bf<<<(512 * 512 / 4 + 255) / 256, 256, 0, stream>>>(W3, wbf, 512 * 512);
  k_f2bf<<<(512 * 512 / 4 + 255) / 256, 256, 0, stream>>>(Wr3, wrbf, 512 * 512);
  k_gemm_bt<<<ggrid, gblk, 0, stream>>>(hA, wbf, feat, N_NODES, 512, 512);
  k_gemm_bt<<<ggrid, gblk, 0, stream>>>(hA, wrbf, hres, N_NODES, 512, 512);
  k_el_er<<<5000, 256, 0, stream>>>(feat, al3, ar3, el, er);
  k_gat_agg<true><<<5000, 256, 0, stream>>>(feat, hres, el, er, indptr, csr_src, nullptr, h3);

  // ---- groups_score (fused pair MLP) ----
  k_pair_mlp<0><<<N_EDGES / 128, 256, 0, stream>>>(h3, src, dst, Wg1, bg1, Wg2, bg2,
                                                   out_groups, N_EDGES);

  // ---- entity path ----
  hipMemsetAsync(ent_sum, 0, (size_t)NENT * 128 * 4, stream);
  hipMemsetAsync(pos_sum, 0, (size_t)NENT * 2 * 4, stream);
  hipMemsetAsync(cnt, 0, (size_t)NENT * 4, stream);
  k_ent_scatter<<<(N_NODES * 32 + 255) / 256, 256, 0, stream>>>(h3, position, entity, ent_sum,
                                                                pos_sum, cnt);
  k_entity_states<<<(NENT * 128 + 255) / 256, 256, 0, stream>>>(ent_sum, We, be, es);
  k_entity_class<<<(NENT * 4 + 255) / 256, 256, 0, stream>>>(es, Wc, bc, out_class);
  k_entity_pos<<<(NENT + 255) / 256, 256, 0, stream>>>(pos_sum, cnt, out_pos, wspos);
  k_knn<<<NENT, 256, 0, stream>>>(wspos, knn);
  // ---- entity_link_score (fused pair MLP over knn pairs) ----
  k_pair_mlp<1><<<(NENT * KNN_K + 127) / 128, 256, 0, stream>>>(es, knn, nullptr, Wl1, bl1,
                                                                Wl2, bl2, out_link,
                                                                NENT * KNN_K);
}

// Round 4
// 545.831 us; speedup vs baseline: 1.7778x; 1.2986x over previous
//
#include <hip/hip_runtime.h>
#include <math.h>

#define N_NODES 20000
#define N_EDGES 320000
#define NENT    2000
#define KNN_K   10

typedef __attribute__((ext_vector_type(4))) float f32x4;
typedef __attribute__((ext_vector_type(8))) short bf16x8;
typedef __attribute__((ext_vector_type(8))) unsigned short u16x8;
typedef __attribute__((ext_vector_type(4))) unsigned short u16x4;

__device__ __forceinline__ unsigned short f2bf(float f) {
  union { float f; unsigned u; } v; v.f = f;
  unsigned r = v.u + 0x7fffu + ((v.u >> 16) & 1u);
  return (unsigned short)(r >> 16);
}
__device__ __forceinline__ float bf2f(unsigned short u) {
  union { unsigned u; float f; } v; v.u = ((unsigned)u) << 16;
  return v.f;
}
__device__ __forceinline__ float sigmoidf(float x) {
  return 1.f / (1.f + __expf(-x));
}

// ---------------- h0 = concat(position, w_embed) -> bf16 ----------------
__global__ void k_build_h0(const float* __restrict__ pos, const float* __restrict__ wemb,
                           unsigned short* __restrict__ h0) {
  int i = blockIdx.x * blockDim.x + threadIdx.x;
  if (i >= N_NODES * 128) return;
  int n = i >> 7, c = i & 127;
  float v = (c < 2) ? pos[n * 2 + c] : wemb[n * 126 + (c - 2)];
  h0[i] = f2bf(v);
}

// ---------------- generic f32 -> bf16 (n multiple of 4) ----------------
__global__ void k_f2bf(const float* __restrict__ in, unsigned short* __restrict__ out, int n) {
  int i = blockIdx.x * blockDim.x + threadIdx.x;
  if (i * 4 >= n) return;
  f32x4 v = *(const f32x4*)(in + i * 4);
  u16x4 o;
  o[0] = f2bf(v[0]); o[1] = f2bf(v[1]); o[2] = f2bf(v[2]); o[3] = f2bf(v[3]);
  *(u16x4*)(out + i * 4) = o;
}

// ---------------- bf16 MFMA GEMM: C[M,Nn] = A[M,K] * B[Nn,K]^T, bf16 out ----------------
__global__ __launch_bounds__(256) void k_gemm_bt(
    const unsigned short* __restrict__ A, const unsigned short* __restrict__ B,
    unsigned short* __restrict__ C, int M, int Nn, int K) {
  __shared__ __align__(16) unsigned short As[128 * 64];
  __shared__ __align__(16) unsigned short Bs[128 * 64];
  const int bm = blockIdx.x * 128, bn = blockIdx.y * 128;
  const int t = threadIdx.x;
  const int l = t & 63, w = t >> 6;
  const int wr = w >> 1, wc = w & 1;
  f32x4 acc[4][4];
#pragma unroll
  for (int m = 0; m < 4; ++m)
#pragma unroll
    for (int n = 0; n < 4; ++n) acc[m][n] = (f32x4){0.f, 0.f, 0.f, 0.f};

  for (int kb = 0; kb < K; kb += 64) {
    __syncthreads();
#pragma unroll
    for (int i = 0; i < 4; ++i) {
      int c = t + 256 * i;         // 1024 16B-chunks per tile
      int row = c >> 3, cc = c & 7;
      int sw = cc ^ (row & 7);     // T2 xor-swizzle (granule)
      int ar = bm + row; if (ar > M - 1) ar = M - 1;
      *(f32x4*)&As[row * 64 + sw * 8] = *(const f32x4*)(A + (size_t)ar * K + kb + cc * 8);
      *(f32x4*)&Bs[row * 64 + sw * 8] = *(const f32x4*)(B + (size_t)(bn + row) * K + kb + cc * 8);
    }
    __syncthreads();
#pragma unroll
    for (int kk = 0; kk < 2; ++kk) {
      bf16x8 af[4], bfr[4];
#pragma unroll
      for (int m = 0; m < 4; ++m) {
        int row = wr * 64 + m * 16 + (l & 15);
        int g = (kk * 4 + (l >> 4)) ^ (row & 7);
        af[m] = *(const bf16x8*)&As[row * 64 + g * 8];
      }
#pragma unroll
      for (int n = 0; n < 4; ++n) {
        int row = wc * 64 + n * 16 + (l & 15);
        int g = (kk * 4 + (l >> 4)) ^ (row & 7);
        bfr[n] = *(const bf16x8*)&Bs[row * 64 + g * 8];
      }
#pragma unroll
      for (int m = 0; m < 4; ++m)
#pragma unroll
        for (int n = 0; n < 4; ++n)
          acc[m][n] = __builtin_amdgcn_mfma_f32_16x16x32_bf16(af[m], bfr[n], acc[m][n], 0, 0, 0);
    }
  }
#pragma unroll
  for (int m = 0; m < 4; ++m) {
    int r0 = bm + wr * 64 + m * 16 + ((l >> 4) << 2);
#pragma unroll
    for (int n = 0; n < 4; ++n) {
      int c0 = bn + wc * 64 + n * 16 + (l & 15);
#pragma unroll
      for (int r = 0; r < 4; ++r) {
        int row = r0 + r;
        if (row < M) C[(size_t)row * Nn + c0] = f2bf(acc[m][n][r]);
      }
    }
  }
}

// ---------------- el/er: per (node, head) dot(feat, al/ar) ----------------
__global__ void k_el_er(const unsigned short* __restrict__ feat, const float* __restrict__ al,
                        const float* __restrict__ ar, float* __restrict__ el,
                        float* __restrict__ er) {
  int wid = (blockIdx.x * blockDim.x + threadIdx.x) >> 6;
  if (wid >= N_NODES) return;
  int l = threadIdx.x & 63;
  int g = l >> 4, q = l & 15;
  u16x8 fv = *(const u16x8*)(feat + (size_t)wid * 512 + l * 8);
  const float* alp = al + g * 128 + q * 8;
  const float* arp = ar + g * 128 + q * 8;
  float sl = 0.f, sr = 0.f;
#pragma unroll
  for (int j = 0; j < 8; ++j) { float f = bf2f(fv[j]); sl += f * alp[j]; sr += f * arp[j]; }
#pragma unroll
  for (int d = 1; d < 16; d <<= 1) { sl += __shfl_xor(sl, d); sr += __shfl_xor(sr, d); }
  if (q == 0) { el[wid * 4 + g] = sl; er[wid * 4 + g] = sr; }
}

// ---------------- CSR build ----------------
__global__ void k_hist(const int* __restrict__ dst, int* __restrict__ indeg) {
  int e = blockIdx.x * blockDim.x + threadIdx.x;
  if (e < N_EDGES) atomicAdd(&indeg[dst[e]], 1);
}

// single-block 1024-thread scan: indptr + cursor init
__global__ __launch_bounds__(1024) void k_scan_fast(const int* __restrict__ indeg,
                                                    int* __restrict__ indptr,
                                                    int* __restrict__ cursor) {
  __shared__ int wsum[16];
  const int t = threadIdx.x;
  const int l = t & 63, w = t >> 6;
  const int CH = 20;  // 1024*20 >= 20000
  int base = t * CH;
  int vals[CH];
  int s = 0;
#pragma unroll
  for (int i = 0; i < CH; ++i) {
    int idx = base + i;
    int v = (idx < N_NODES) ? indeg[idx] : 0;
    vals[i] = v;
    s += v;
  }
  int ss = s;
#pragma unroll
  for (int d = 1; d < 64; d <<= 1) { int o = __shfl_up(ss, d); if (l >= d) ss += o; }
  if (l == 63) wsum[w] = ss;
  __syncthreads();
  if (t < 16) {
    int v = wsum[t];
#pragma unroll
    for (int d = 1; d < 16; d <<= 1) { int o = __shfl_up(v, d); if (t >= d) v += o; }
    wsum[t] = v;
  }
  __syncthreads();
  int run = ((w > 0) ? wsum[w - 1] : 0) + ss - s;  // exclusive prefix of this thread
  if (t == 0) indptr[0] = 0;
#pragma unroll
  for (int i = 0; i < CH; ++i) {
    int idx = base + i;
    if (idx < N_NODES) {
      cursor[idx] = run;
      run += vals[i];
      indptr[idx + 1] = run;
    }
  }
}

__global__ void k_scatter(const int* __restrict__ src, const int* __restrict__ dst,
                          int* __restrict__ cursor, int* __restrict__ csr_src) {
  int e = blockIdx.x * blockDim.x + threadIdx.x;
  if (e < N_EDGES) {
    int p = atomicAdd(&cursor[dst[e]], 1);
    csr_src[p] = src[e];
  }
}

// ---------------- GAT edge-softmax + aggregation (wave per dst node) ----------------
template <bool FINAL>
__global__ void k_gat_agg(const unsigned short* __restrict__ feat,
                          const unsigned short* __restrict__ hres,
                          const float* __restrict__ el, const float* __restrict__ er,
                          const int* __restrict__ indptr, const int* __restrict__ csr_src,
                          unsigned short* __restrict__ hnext, float* __restrict__ h3,
                          unsigned short* __restrict__ h3b) {
  int wid = (blockIdx.x * blockDim.x + threadIdx.x) >> 6;
  if (wid >= N_NODES) return;
  int l = threadIdx.x & 63;
  int g = l >> 4;
  int beg = indptr[wid], end = indptr[wid + 1];
  f32x4 er4 = *(const f32x4*)(er + wid * 4);
  const float NI = -__builtin_inff();
  f32x4 mx = (f32x4){NI, NI, NI, NI};
  for (int j = beg + l; j < end; j += 64) {
    int s = csr_src[j];
    f32x4 el4 = *(const f32x4*)(el + s * 4);
#pragma unroll
    for (int h = 0; h < 4; ++h) {
      float v = el4[h] + er4[h];
      v = (v >= 0.f) ? v : 0.2f * v;
      mx[h] = fmaxf(mx[h], v);
    }
  }
#pragma unroll
  for (int d = 1; d < 64; d <<= 1) {
#pragma unroll
    for (int h = 0; h < 4; ++h) mx[h] = fmaxf(mx[h], __shfl_xor(mx[h], d));
  }
  float m_g = mx[g];
  float er_g = er4[g];
  float asum = 0.f;
  float acc[8];
#pragma unroll
  for (int j = 0; j < 8; ++j) acc[j] = 0.f;
  for (int j = beg; j < end; ++j) {
    int s = csr_src[j];
    float ev = el[s * 4 + g] + er_g;
    ev = (ev >= 0.f) ? ev : 0.2f * ev;
    float p = __expf(ev - m_g);
    asum += p;
    u16x8 fv = *(const u16x8*)(feat + (size_t)s * 512 + l * 8);
#pragma unroll
    for (int j2 = 0; j2 < 8; ++j2) acc[j2] += p * bf2f(fv[j2]);
  }
  float inv = (end > beg) ? 1.f / asum : 1.f;
  u16x8 hv = *(const u16x8*)(hres + (size_t)wid * 512 + l * 8);
  float o[8];
#pragma unroll
  for (int j = 0; j < 8; ++j) o[j] = acc[j] * inv + bf2f(hv[j]);
  if constexpr (!FINAL) {
    u16x8 ob;
#pragma unroll
    for (int j = 0; j < 8; ++j) ob[j] = f2bf(fmaxf(o[j], 0.f));
    *(u16x8*)(hnext + (size_t)wid * 512 + l * 8) = ob;
  } else {
#pragma unroll
    for (int j = 0; j < 8; ++j) {
      float v = o[j];
      v += __shfl_xor(v, 16);
      v += __shfl_xor(v, 32);
      o[j] = v * 0.25f;
    }
    if (g == 0) {
      f32x4 o0 = (f32x4){o[0], o[1], o[2], o[3]};
      f32x4 o1 = (f32x4){o[4], o[5], o[6], o[7]};
      *(f32x4*)(h3 + (size_t)wid * 128 + l * 8) = o0;
      *(f32x4*)(h3 + (size_t)wid * 128 + l * 8 + 4) = o1;
      u16x8 hb;
#pragma unroll
      for (int j = 0; j < 8; ++j) hb[j] = f2bf(o[j]);
      *(u16x8*)(h3b + (size_t)wid * 128 + l * 8) = hb;
    }
  }
}

// ---- fused pair MLP: sigmoid(relu(|X[a]-X[b]| @ W1^T + b1) @ W2^T + b2) ----
// X is bf16 rows of 128.
// MODE 0: a=ia[e], b=ib[e] (groups_score, npairs multiple of 128)
// MODE 1: a=ia[e] (knn flat), b=e/KNN_K (entity_link_score, tail-guarded)
template <int MODE>
__global__ __launch_bounds__(256) void k_pair_mlp(
    const unsigned short* __restrict__ X, const int* __restrict__ ia,
    const int* __restrict__ ib,
    const float* __restrict__ W1, const float* __restrict__ b1,
    const float* __restrict__ W2, const float* __restrict__ b2,
    float* __restrict__ out, int npairs) {
  __shared__ __align__(16) unsigned short Xs[128 * 128];
  __shared__ __align__(16) unsigned short Ws[128 * 128];
  const int t = threadIdx.x;
  const int l = t & 63, w = t >> 6, wr = w >> 1, wc = w & 1;
  const int e0 = blockIdx.x * 128;
  {
    int r = t >> 1, hf = t & 1;
    int e = e0 + r;
    if (MODE == 1 && e >= npairs) e = npairs - 1;
    int sa, sb;
    if (MODE == 0) { sa = ia[e]; sb = ib[e]; }
    else           { sa = ia[e]; sb = e / KNN_K; }
    const unsigned short* pa = X + (size_t)sa * 128 + hf * 64;
    const unsigned short* pb = X + (size_t)sb * 128 + hf * 64;
    const float* pw = W1 + (size_t)r * 128 + hf * 64;
#pragma unroll
    for (int c = 0; c < 64; c += 8) {
      u16x8 av = *(const u16x8*)(pa + c);
      u16x8 bv = *(const u16x8*)(pb + c);
      f32x4 w0 = *(const f32x4*)(pw + c), w1 = *(const f32x4*)(pw + c + 4);
      u16x8 xv, wv;
#pragma unroll
      for (int j = 0; j < 8; ++j) xv[j] = f2bf(fabsf(bf2f(av[j]) - bf2f(bv[j])));
#pragma unroll
      for (int j = 0; j < 4; ++j) { wv[j] = f2bf(w0[j]); wv[j + 4] = f2bf(w1[j]); }
      int gb = hf * 8 + (c >> 3);
      *(u16x8*)&Xs[r * 128 + (gb ^ (r & 15)) * 8] = xv;
      *(u16x8*)&Ws[r * 128 + (gb ^ (r & 15)) * 8] = wv;
    }
  }
  __syncthreads();
  f32x4 acc[4][4];
#pragma unroll
  for (int m = 0; m < 4; ++m)
#pragma unroll
    for (int n = 0; n < 4; ++n) acc[m][n] = (f32x4){0.f, 0.f, 0.f, 0.f};
#pragma unroll
  for (int kk = 0; kk < 4; ++kk) {
    bf16x8 af[4], bfr[4];
#pragma unroll
    for (int m = 0; m < 4; ++m) {
      int row = wr * 64 + m * 16 + (l & 15);
      int gsw = (kk * 4 + (l >> 4)) ^ (row & 15);
      af[m] = *(const bf16x8*)&Xs[row * 128 + gsw * 8];
    }
#pragma unroll
    for (int n = 0; n < 4; ++n) {
      int row = wc * 64 + n * 16 + (l & 15);
      int gsw = (kk * 4 + (l >> 4)) ^ (row & 15);
      bfr[n] = *(const bf16x8*)&Ws[row * 128 + gsw * 8];
    }
#pragma unroll
    for (int m = 0; m < 4; ++m)
#pragma unroll
      for (int n = 0; n < 4; ++n)
        acc[m][n] = __builtin_amdgcn_mfma_f32_16x16x32_bf16(af[m], bfr[n], acc[m][n], 0, 0, 0);
  }
  float part[4][4];
#pragma unroll
  for (int m = 0; m < 4; ++m)
#pragma unroll
    for (int r = 0; r < 4; ++r) part[m][r] = 0.f;
#pragma unroll
  for (int n = 0; n < 4; ++n) {
    int col = wc * 64 + n * 16 + (l & 15);
    float bb = b1[col], w2 = W2[col];
#pragma unroll
    for (int m = 0; m < 4; ++m)
#pragma unroll
      for (int r = 0; r < 4; ++r) {
        float y = fmaxf(acc[m][n][r] + bb, 0.f);
        part[m][r] += y * w2;
      }
  }
#pragma unroll
  for (int d = 1; d < 16; d <<= 1)
#pragma unroll
    for (int m = 0; m < 4; ++m)
#pragma unroll
      for (int r = 0; r < 4; ++r) part[m][r] += __shfl_xor(part[m][r], d);
  __syncthreads();  // safe to alias Xs now
  float* sc = (float*)Xs;
  if ((l & 15) == 0) {
#pragma unroll
    for (int m = 0; m < 4; ++m)
#pragma unroll
      for (int r = 0; r < 4; ++r)
        sc[wc * 128 + wr * 64 + m * 16 + (l >> 4) * 4 + r] = part[m][r];
  }
  __syncthreads();
  if (t < 128 && (MODE == 0 || e0 + t < npairs)) {
    float logit = sc[t] + sc[128 + t] + b2[0];
    out[e0 + t] = sigmoidf(logit);
  }
}

// ---------------- entity segment sums ----------------
__global__ void k_ent_scatter(const float* __restrict__ h3, const float* __restrict__ pos,
                              const int* __restrict__ entity, float* __restrict__ ent_sum,
                              float* __restrict__ pos_sum, float* __restrict__ cnt) {
  int i = blockIdx.x * blockDim.x + threadIdx.x;
  if (i >= N_NODES * 32) return;
  int n = i >> 5, c = i & 31;
  int e = entity[n];
  f32x4 v = *(const f32x4*)(h3 + (size_t)n * 128 + c * 4);
  atomicAdd(&ent_sum[e * 128 + c * 4 + 0], v[0]);
  atomicAdd(&ent_sum[e * 128 + c * 4 + 1], v[1]);
  atomicAdd(&ent_sum[e * 128 + c * 4 + 2], v[2]);
  atomicAdd(&ent_sum[e * 128 + c * 4 + 3], v[3]);
  if (c == 0) {
    atomicAdd(&pos_sum[e * 2 + 0], pos[n * 2 + 0]);
    atomicAdd(&pos_sum[e * 2 + 1], pos[n * 2 + 1]);
    atomicAdd(&cnt[e], 1.f);
  }
}

__global__ void k_entity_states(const float* __restrict__ ent_sum, const float* __restrict__ We,
                                const float* __restrict__ be, float* __restrict__ es) {
  int i = blockIdx.x * blockDim.x + threadIdx.x;
  if (i >= NENT * 128) return;
  int e = i >> 7, j = i & 127;
  const float* x = ent_sum + (size_t)e * 128;
  const float* wrow = We + (size_t)j * 128;
  float s = be[j];
  for (int k = 0; k < 128; k += 4) {
    f32x4 xv = *(const f32x4*)(x + k);
    f32x4 wv = *(const f32x4*)(wrow + k);
    s += xv[0] * wv[0] + xv[1] * wv[1] + xv[2] * wv[2] + xv[3] * wv[3];
  }
  es[i] = s;
}

__global__ void k_entity_class(const float* __restrict__ es, const float* __restrict__ Wc,
                               const float* __restrict__ bc, float* __restrict__ out) {
  int i = blockIdx.x * blockDim.x + threadIdx.x;
  if (i >= NENT * 4) return;
  int e = i >> 2, c = i & 3;
  const float* x = es + (size_t)e * 128;
  const float* wrow = Wc + (size_t)c * 128;
  float s = bc[c];
  for (int k = 0; k < 128; ++k) s += x[k] * wrow[k];
  out[i] = sigmoidf(s);
}

__global__ void k_entity_pos(const float* __restrict__ pos_sum, const float* __restrict__ cnt,
                             float* __restrict__ outpos, float* __restrict__ wspos) {
  int e = blockIdx.x * blockDim.x + threadIdx.x;
  if (e >= NENT) return;
  float c = fmaxf(cnt[e], 1.f);
  float x = pos_sum[e * 2] / c, y = pos_sum[e * 2 + 1] / c;
  outpos[e * 2] = x; outpos[e * 2 + 1] = y;
  wspos[e * 2] = x; wspos[e * 2 + 1] = y;
}

// ---------------- exact knn (K smallest d2, ties -> smaller index) ----------------
__global__ __launch_bounds__(256) void k_knn(const float* __restrict__ entpos,
                                             int* __restrict__ knn) {
  __shared__ float d2row[NENT];
  __shared__ float rv[256];
  __shared__ int ri[256];
  int i = blockIdx.x, t = threadIdx.x;
  float px = entpos[i * 2], py = entpos[i * 2 + 1];
  for (int j = t; j < NENT; j += 256) {
    float dx = px - entpos[j * 2], dy = py - entpos[j * 2 + 1];
    d2row[j] = __fadd_rn(__fmul_rn(dx, dx), __fmul_rn(dy, dy));
  }
  __syncthreads();
  for (int k = 0; k < KNN_K; ++k) {
    float bv = __builtin_inff(); int bi = 0x7fffffff;
    for (int j = t; j < NENT; j += 256) {
      float v = d2row[j];
      if (v < bv) { bv = v; bi = j; }
    }
    rv[t] = bv; ri[t] = bi;
    __syncthreads();
    for (int s = 128; s > 0; s >>= 1) {
      if (t < s) {
        if (rv[t + s] < rv[t] || (rv[t + s] == rv[t] && ri[t + s] < ri[t])) {
          rv[t] = rv[t + s]; ri[t] = ri[t + s];
        }
      }
      __syncthreads();
    }
    if (t == 0) { knn[i * KNN_K + k] = ri[0]; d2row[ri[0]] = __builtin_inff(); }
    __syncthreads();
  }
}

// =======================================================================
extern "C" void kernel_launch(void* const* d_in, const int* in_sizes, int n_in,
                              void* d_out, int out_size, void* d_ws, size_t ws_size,
                              hipStream_t stream) {
  const float* position = (const float*)d_in[0];
  const float* w_embed  = (const float*)d_in[1];
  const int*   src      = (const int*)d_in[2];
  const int*   dst      = (const int*)d_in[3];
  const int*   entity   = (const int*)d_in[4];
  const float* W1 = (const float*)d_in[5];
  const float* al1 = (const float*)d_in[6];
  const float* ar1 = (const float*)d_in[7];
  const float* Wr1 = (const float*)d_in[8];
  const float* W2 = (const float*)d_in[9];
  const float* al2 = (const float*)d_in[10];
  const float* ar2 = (const float*)d_in[11];
  const float* Wr2 = (const float*)d_in[12];
  const float* W3 = (const float*)d_in[13];
  const float* al3 = (const float*)d_in[14];
  const float* ar3 = (const float*)d_in[15];
  const float* Wr3 = (const float*)d_in[16];
  const float* Wg1 = (const float*)d_in[17];
  const float* bg1 = (const float*)d_in[18];
  const float* Wg2 = (const float*)d_in[19];
  const float* bg2 = (const float*)d_in[20];
  const float* We  = (const float*)d_in[21];
  const float* be  = (const float*)d_in[22];
  const float* Wl1 = (const float*)d_in[23];
  const float* bl1 = (const float*)d_in[24];
  const float* Wl2 = (const float*)d_in[25];
  const float* bl2 = (const float*)d_in[26];
  const float* Wc  = (const float*)d_in[27];
  const float* bc  = (const float*)d_in[28];

  float* out_groups = (float*)d_out;
  float* out_class  = out_groups + N_EDGES;
  float* out_pos    = out_class + NENT * 4;
  float* out_link   = out_pos + NENT * 2;

  char* ws = (char*)d_ws;
  size_t off = 0;
  auto carve = [&](size_t bytes) -> char* {
    char* p = ws + off;
    off = (off + bytes + 255) & ~(size_t)255;
    return p;
  };
  unsigned short* feat = (unsigned short*)carve((size_t)N_NODES * 512 * 2);
  unsigned short* hres = (unsigned short*)carve((size_t)N_NODES * 512 * 2);
  unsigned short* hA = (unsigned short*)carve((size_t)N_NODES * 512 * 2);
  unsigned short* hB = (unsigned short*)carve((size_t)N_NODES * 512 * 2);
  unsigned short* wbf = (unsigned short*)carve(512 * 512 * 2);
  unsigned short* wrbf = (unsigned short*)carve(512 * 512 * 2);
  float* el = (float*)carve((size_t)N_NODES * 4 * 4);
  float* er = (float*)carve((size_t)N_NODES * 4 * 4);
  int* indeg = (int*)carve((size_t)N_NODES * 4);
  int* indptr = (int*)carve((size_t)(N_NODES + 1) * 4);
  int* cursor = (int*)carve((size_t)N_NODES * 4);
  int* csr_src = (int*)carve((size_t)N_EDGES * 4);
  float* h3 = (float*)carve((size_t)N_NODES * 128 * 4);
  unsigned short* h3b = (unsigned short*)carve((size_t)N_NODES * 128 * 2);
  float* ent_sum = (float*)carve((size_t)NENT * 128 * 4);
  float* pos_sum = (float*)carve((size_t)NENT * 2 * 4);
  float* cnt = (float*)carve((size_t)NENT * 4);
  float* es = (float*)carve((size_t)NENT * 128 * 4);
  unsigned short* esb = (unsigned short*)carve((size_t)NENT * 128 * 2);
  float* wspos = (float*)carve((size_t)NENT * 2 * 4);
  int* knn = (int*)carve((size_t)NENT * KNN_K * 4);

  // ---- CSR over dst (shared by all 3 GAT layers) ----
  hipMemsetAsync(indeg, 0, (size_t)N_NODES * 4, stream);
  k_hist<<<(N_EDGES + 255) / 256, 256, 0, stream>>>(dst, indeg);
  k_scan_fast<<<1, 1024, 0, stream>>>(indeg, indptr, cursor);
  k_scatter<<<(N_EDGES + 255) / 256, 256, 0, stream>>>(src, dst, cursor, csr_src);

  k_build_h0<<<(N_NODES * 128 + 255) / 256, 256, 0, stream>>>(position, w_embed, hA);

  dim3 ggrid((N_NODES + 127) / 128, 4), gblk(256);

  // ---- layer 1 (K=128) ----
  k_f2bf<<<(512 * 128 / 4 + 255) / 256, 256, 0, stream>>>(W1, wbf, 512 * 128);
  k_f2bf<<<(512 * 128 / 4 + 255) / 256, 256, 0, stream>>>(Wr1, wrbf, 512 * 128);
  k_gemm_bt<<<ggrid, gblk, 0, stream>>>(hA, wbf, feat, N_NODES, 512, 128);
  k_gemm_bt<<<ggrid, gblk, 0, stream>>>(hA, wrbf, hres, N_NODES, 512, 128);
  k_el_er<<<5000, 256, 0, stream>>>(feat, al1, ar1, el, er);
  k_gat_agg<false><<<5000, 256, 0, stream>>>(feat, hres, el, er, indptr, csr_src, hB,
                                             nullptr, nullptr);

  // ---- layer 2 (K=512) ----
  k_f2bf<<<(512 * 512 / 4 + 255) / 256, 256, 0, stream>>>(W2, wbf, 512 * 512);
  k_f2bf<<<(512 * 512 / 4 + 255) / 256, 256, 0, stream>>>(Wr2, wrbf, 512 * 512);
  k_gemm_bt<<<ggrid, gblk, 0, stream>>>(hB, wbf, feat, N_NODES, 512, 512);
  k_gemm_bt<<<ggrid, gblk, 0, stream>>>(hB, wrbf, hres, N_NODES, 512, 512);
  k_el_er<<<5000, 256, 0, stream>>>(feat, al2, ar2, el, er);
  k_gat_agg<false><<<5000, 256, 0, stream>>>(feat, hres, el, er, indptr, csr_src, hA,
                                             nullptr, nullptr);

  // ---- layer 3 (K=512, no relu, head-mean) ----
  k_f2bf<<<(512 * 512 / 4 + 255) / 256, 256, 0, stream>>>(W3, wbf, 512 * 512);
  k_f2bf<<<(512 * 512 / 4 + 255) / 256, 256, 0, stream>>>(Wr3, wrbf, 512 * 512);
  k_gemm_bt<<<ggrid, gblk, 0, stream>>>(hA, wbf, feat, N_NODES, 512, 512);
  k_gemm_bt<<<ggrid, gblk, 0, stream>>>(hA, wrbf, hres, N_NODES, 512, 512);
  k_el_er<<<5000, 256, 0, stream>>>(feat, al3, ar3, el, er);
  k_gat_agg<true><<<5000, 256, 0, stream>>>(feat, hres, el, er, indptr, csr_src, nullptr,
                                            h3, h3b);

  // ---- groups_score (fused pair MLP on bf16 h3) ----
  k_pair_mlp<0><<<N_EDGES / 128, 256, 0, stream>>>(h3b, src, dst, Wg1, bg1, Wg2, bg2,
                                                   out_groups, N_EDGES);

  // ---- entity path ----
  hipMemsetAsync(ent_sum, 0, (size_t)NENT * 128 * 4, stream);
  hipMemsetAsync(pos_sum, 0, (size_t)NENT * 2 * 4, stream);
  hipMemsetAsync(cnt, 0, (size_t)NENT * 4, stream);
  k_ent_scatter<<<(N_NODES * 32 + 255) / 256, 256, 0, stream>>>(h3, position, entity, ent_sum,
                                                                pos_sum, cnt);
  k_entity_states<<<(NENT * 128 + 255) / 256, 256, 0, stream>>>(ent_sum, We, be, es);
  k_entity_class<<<(NENT * 4 + 255) / 256, 256, 0, stream>>>(es, Wc, bc, out_class);
  k_entity_pos<<<(NENT + 255) / 256, 256, 0, stream>>>(pos_sum, cnt, out_pos, wspos);
  k_knn<<<NENT, 256, 0, stream>>>(wspos, knn);
  k_f2bf<<<(NENT * 128 / 4 + 255) / 256, 256, 0, stream>>>(es, esb, NENT * 128);
  // ---- entity_link_score (fused pair MLP over knn pairs) ----
  k_pair_mlp<1><<<(NENT * KNN_K + 127) / 128, 256, 0, stream>>>(esb, knn, nullptr, Wl1, bl1,
                                                                Wl2, bl2, out_link,
                                                                NENT * KNN_K);
}

// Round 5
// 521.113 us; speedup vs baseline: 1.8621x; 1.0474x over previous
//
#include <hip/hip_runtime.h>
#include <math.h>

#define N_NODES 20000
#define N_EDGES 320000
#define NENT    2000
#define KNN_K   10

typedef __attribute__((ext_vector_type(4))) float f32x4;
typedef __attribute__((ext_vector_type(8))) short bf16x8;
typedef __attribute__((ext_vector_type(8))) unsigned short u16x8;
typedef __attribute__((ext_vector_type(4))) unsigned short u16x4;

__device__ __forceinline__ unsigned short f2bf(float f) {
  union { float f; unsigned u; } v; v.f = f;
  unsigned r = v.u + 0x7fffu + ((v.u >> 16) & 1u);
  return (unsigned short)(r >> 16);
}
__device__ __forceinline__ float bf2f(unsigned short u) {
  union { unsigned u; float f; } v; v.u = ((unsigned)u) << 16;
  return v.f;
}
__device__ __forceinline__ float sigmoidf(float x) {
  return 1.f / (1.f + __expf(-x));
}
// async global->LDS, 16B per lane; lds dest = wave-uniform base + lane*16
__device__ __forceinline__ void gload_lds16(const unsigned short* g, unsigned short* lds) {
  __builtin_amdgcn_global_load_lds(
      (const __attribute__((address_space(1))) unsigned int*)g,
      (__attribute__((address_space(3))) unsigned int*)lds, 16, 0, 0);
}

// ---------------- h0 = concat(position, w_embed) -> bf16 ----------------
__global__ void k_build_h0(const float* __restrict__ pos, const float* __restrict__ wemb,
                           unsigned short* __restrict__ h0) {
  int i = blockIdx.x * blockDim.x + threadIdx.x;
  if (i >= N_NODES * 128) return;
  int n = i >> 7, c = i & 127;
  float v = (c < 2) ? pos[n * 2 + c] : wemb[n * 126 + (c - 2)];
  h0[i] = f2bf(v);
}

// ---------------- generic f32 -> bf16 (n multiple of 4) ----------------
__global__ void k_f2bf(const float* __restrict__ in, unsigned short* __restrict__ out, int n) {
  int i = blockIdx.x * blockDim.x + threadIdx.x;
  if (i * 4 >= n) return;
  f32x4 v = *(const f32x4*)(in + i * 4);
  u16x4 o;
  o[0] = f2bf(v[0]); o[1] = f2bf(v[1]); o[2] = f2bf(v[2]); o[3] = f2bf(v[3]);
  *(u16x4*)(out + i * 4) = o;
}

// ------- bf16 MFMA GEMM: C[M,Nc] = A[M,K] * B[Nc,K]^T, bf16 out, stride Nc -------
// staging via global_load_lds (linear LDS dest, source-granule XOR pre-swizzle)
__global__ __launch_bounds__(256) void k_gemm_bt(
    const unsigned short* __restrict__ A, const unsigned short* __restrict__ B,
    unsigned short* __restrict__ C, int M, int Nc, int K) {
  __shared__ __align__(16) unsigned short As[128 * 64];
  __shared__ __align__(16) unsigned short Bs[128 * 64];
  const int bm = blockIdx.x * 128, bn = blockIdx.y * 128;
  const int t = threadIdx.x;
  const int l = t & 63, w = t >> 6;
  const int wr = w >> 1, wc = w & 1;
  f32x4 acc[4][4];
#pragma unroll
  for (int m = 0; m < 4; ++m)
#pragma unroll
    for (int n = 0; n < 4; ++n) acc[m][n] = (f32x4){0.f, 0.f, 0.f, 0.f};

  for (int kb = 0; kb < K; kb += 64) {
    __syncthreads();
#pragma unroll
    for (int i = 0; i < 4; ++i) {
      int c = t + 256 * i;         // 1024 16B-chunks per tile
      int row = c >> 3, cc = c & 7;
      int scc = cc ^ (row & 7);    // pre-swizzled SOURCE granule (read side keeps same XOR)
      int ar = bm + row; if (ar > M - 1) ar = M - 1;
      gload_lds16(A + (size_t)ar * K + kb + scc * 8, &As[(size_t)(w * 64 + 256 * i) * 8]);
      gload_lds16(B + (size_t)(bn + row) * K + kb + scc * 8,
                  &Bs[(size_t)(w * 64 + 256 * i) * 8]);
    }
    __syncthreads();
#pragma unroll
    for (int kk = 0; kk < 2; ++kk) {
      bf16x8 af[4], bfr[4];
#pragma unroll
      for (int m = 0; m < 4; ++m) {
        int row = wr * 64 + m * 16 + (l & 15);
        int g = (kk * 4 + (l >> 4)) ^ (row & 7);
        af[m] = *(const bf16x8*)&As[row * 64 + g * 8];
      }
#pragma unroll
      for (int n = 0; n < 4; ++n) {
        int row = wc * 64 + n * 16 + (l & 15);
        int g = (kk * 4 + (l >> 4)) ^ (row & 7);
        bfr[n] = *(const bf16x8*)&Bs[row * 64 + g * 8];
      }
#pragma unroll
      for (int m = 0; m < 4; ++m)
#pragma unroll
        for (int n = 0; n < 4; ++n)
          acc[m][n] = __builtin_amdgcn_mfma_f32_16x16x32_bf16(af[m], bfr[n], acc[m][n], 0, 0, 0);
    }
  }
#pragma unroll
  for (int m = 0; m < 4; ++m) {
    int r0 = bm + wr * 64 + m * 16 + ((l >> 4) << 2);
#pragma unroll
    for (int n = 0; n < 4; ++n) {
      int c0 = bn + wc * 64 + n * 16 + (l & 15);
#pragma unroll
      for (int r = 0; r < 4; ++r) {
        int row = r0 + r;
        if (row < M) C[(size_t)row * Nc + c0] = f2bf(acc[m][n][r]);
      }
    }
  }
}

// ---------------- el/er: per (node, head) dot(feat, al/ar) ----------------
__global__ void k_el_er(const unsigned short* __restrict__ feat, int fstride,
                        const float* __restrict__ al, const float* __restrict__ ar,
                        float* __restrict__ el, float* __restrict__ er) {
  int wid = (blockIdx.x * blockDim.x + threadIdx.x) >> 6;
  if (wid >= N_NODES) return;
  int l = threadIdx.x & 63;
  int g = l >> 4, q = l & 15;
  u16x8 fv = *(const u16x8*)(feat + (size_t)wid * fstride + l * 8);
  const float* alp = al + g * 128 + q * 8;
  const float* arp = ar + g * 128 + q * 8;
  float sl = 0.f, sr = 0.f;
#pragma unroll
  for (int j = 0; j < 8; ++j) { float f = bf2f(fv[j]); sl += f * alp[j]; sr += f * arp[j]; }
#pragma unroll
  for (int d = 1; d < 16; d <<= 1) { sl += __shfl_xor(sl, d); sr += __shfl_xor(sr, d); }
  if (q == 0) { el[wid * 4 + g] = sl; er[wid * 4 + g] = sr; }
}

// ---------------- CSR build ----------------
__global__ void k_hist(const int* __restrict__ dst, int* __restrict__ indeg) {
  int e = blockIdx.x * blockDim.x + threadIdx.x;
  if (e < N_EDGES) atomicAdd(&indeg[dst[e]], 1);
}

__global__ __launch_bounds__(1024) void k_scan_fast(const int* __restrict__ indeg,
                                                    int* __restrict__ indptr,
                                                    int* __restrict__ cursor) {
  __shared__ int wsum[16];
  const int t = threadIdx.x;
  const int l = t & 63, w = t >> 6;
  const int CH = 20;  // 1024*20 >= 20000
  int base = t * CH;
  int vals[CH];
  int s = 0;
#pragma unroll
  for (int i = 0; i < CH; ++i) {
    int idx = base + i;
    int v = (idx < N_NODES) ? indeg[idx] : 0;
    vals[i] = v;
    s += v;
  }
  int ss = s;
#pragma unroll
  for (int d = 1; d < 64; d <<= 1) { int o = __shfl_up(ss, d); if (l >= d) ss += o; }
  if (l == 63) wsum[w] = ss;
  __syncthreads();
  if (t < 16) {
    int v = wsum[t];
#pragma unroll
    for (int d = 1; d < 16; d <<= 1) { int o = __shfl_up(v, d); if (t >= d) v += o; }
    wsum[t] = v;
  }
  __syncthreads();
  int run = ((w > 0) ? wsum[w - 1] : 0) + ss - s;
  if (t == 0) indptr[0] = 0;
#pragma unroll
  for (int i = 0; i < CH; ++i) {
    int idx = base + i;
    if (idx < N_NODES) {
      cursor[idx] = run;
      run += vals[i];
      indptr[idx + 1] = run;
    }
  }
}

__global__ void k_scatter(const int* __restrict__ src, const int* __restrict__ dst,
                          int* __restrict__ cursor, int* __restrict__ csr_src) {
  int e = blockIdx.x * blockDim.x + threadIdx.x;
  if (e < N_EDGES) {
    int p = atomicAdd(&cursor[dst[e]], 1);
    csr_src[p] = src[e];
  }
}

// ---------------- GAT edge-softmax + aggregation (wave per dst node) ----------------
template <bool FINAL>
__global__ void k_gat_agg(const unsigned short* __restrict__ feat,
                          const unsigned short* __restrict__ hres, int fstride,
                          const float* __restrict__ el, const float* __restrict__ er,
                          const int* __restrict__ indptr, const int* __restrict__ csr_src,
                          unsigned short* __restrict__ hnext, float* __restrict__ h3,
                          unsigned short* __restrict__ h3b) {
  int wid = (blockIdx.x * blockDim.x + threadIdx.x) >> 6;
  if (wid >= N_NODES) return;
  int l = threadIdx.x & 63;
  int g = l >> 4;
  int beg = indptr[wid], end = indptr[wid + 1];
  f32x4 er4 = *(const f32x4*)(er + wid * 4);
  const float NI = -__builtin_inff();
  f32x4 mx = (f32x4){NI, NI, NI, NI};
  for (int j = beg + l; j < end; j += 64) {
    int s = csr_src[j];
    f32x4 el4 = *(const f32x4*)(el + s * 4);
#pragma unroll
    for (int h = 0; h < 4; ++h) {
      float v = el4[h] + er4[h];
      v = (v >= 0.f) ? v : 0.2f * v;
      mx[h] = fmaxf(mx[h], v);
    }
  }
#pragma unroll
  for (int d = 1; d < 64; d <<= 1) {
#pragma unroll
    for (int h = 0; h < 4; ++h) mx[h] = fmaxf(mx[h], __shfl_xor(mx[h], d));
  }
  float m_g = mx[g];
  float er_g = er4[g];
  float asum = 0.f;
  float acc[8];
#pragma unroll
  for (int j = 0; j < 8; ++j) acc[j] = 0.f;
  for (int j = beg; j < end; ++j) {
    int s = csr_src[j];
    float ev = el[s * 4 + g] + er_g;
    ev = (ev >= 0.f) ? ev : 0.2f * ev;
    float p = __expf(ev - m_g);
    asum += p;
    u16x8 fv = *(const u16x8*)(feat + (size_t)s * fstride + l * 8);
#pragma unroll
    for (int j2 = 0; j2 < 8; ++j2) acc[j2] += p * bf2f(fv[j2]);
  }
  float inv = (end > beg) ? 1.f / asum : 1.f;
  u16x8 hv = *(const u16x8*)(hres + (size_t)wid * fstride + l * 8);
  float o[8];
#pragma unroll
  for (int j = 0; j < 8; ++j) o[j] = acc[j] * inv + bf2f(hv[j]);
  if constexpr (!FINAL) {
    u16x8 ob;
#pragma unroll
    for (int j = 0; j < 8; ++j) ob[j] = f2bf(fmaxf(o[j], 0.f));
    *(u16x8*)(hnext + (size_t)wid * 512 + l * 8) = ob;
  } else {
#pragma unroll
    for (int j = 0; j < 8; ++j) {
      float v = o[j];
      v += __shfl_xor(v, 16);
      v += __shfl_xor(v, 32);
      o[j] = v * 0.25f;
    }
    if (g == 0) {
      f32x4 o0 = (f32x4){o[0], o[1], o[2], o[3]};
      f32x4 o1 = (f32x4){o[4], o[5], o[6], o[7]};
      *(f32x4*)(h3 + (size_t)wid * 128 + l * 8) = o0;
      *(f32x4*)(h3 + (size_t)wid * 128 + l * 8 + 4) = o1;
      u16x8 hb;
#pragma unroll
      for (int j = 0; j < 8; ++j) hb[j] = f2bf(o[j]);
      *(u16x8*)(h3b + (size_t)wid * 128 + l * 8) = hb;
    }
  }
}

// ---- fused pair MLP: sigmoid(relu(|X[a]-X[b]| @ W1^T + b1) @ W2^T + b2) ----
// X bf16 rows of 128; Wb bf16 [128,128] row-major, fetched per-fragment from L2.
// MODE 0: a=ia[e], b=ib[e]; MODE 1: a=ia[e] (knn flat), b=e/KNN_K (tail-guarded)
template <int MODE>
__global__ __launch_bounds__(256) void k_pair_mlp(
    const unsigned short* __restrict__ X, const int* __restrict__ ia,
    const int* __restrict__ ib, const unsigned short* __restrict__ Wb,
    const float* __restrict__ b1, const float* __restrict__ W2,
    const float* __restrict__ b2, float* __restrict__ out, int npairs) {
  __shared__ __align__(16) unsigned short Xs[128 * 128];
  const int t = threadIdx.x;
  const int l = t & 63, w = t >> 6, wr = w >> 1, wc = w & 1;
  const int e0 = blockIdx.x * 128;
  {
    int r = t >> 1, hf = t & 1;
    int e = e0 + r;
    if (MODE == 1 && e >= npairs) e = npairs - 1;
    int sa, sb;
    if (MODE == 0) { sa = ia[e]; sb = ib[e]; }
    else           { sa = ia[e]; sb = e / KNN_K; }
    const unsigned short* pa = X + (size_t)sa * 128 + hf * 64;
    const unsigned short* pb = X + (size_t)sb * 128 + hf * 64;
#pragma unroll
    for (int c = 0; c < 64; c += 8) {
      u16x8 av = *(const u16x8*)(pa + c);
      u16x8 bv = *(const u16x8*)(pb + c);
      u16x8 xv;
#pragma unroll
      for (int j = 0; j < 8; ++j) xv[j] = f2bf(fabsf(bf2f(av[j]) - bf2f(bv[j])));
      int gb = hf * 8 + (c >> 3);
      *(u16x8*)&Xs[r * 128 + (gb ^ (r & 15)) * 8] = xv;
    }
  }
  __syncthreads();
  f32x4 acc[4][4];
#pragma unroll
  for (int m = 0; m < 4; ++m)
#pragma unroll
    for (int n = 0; n < 4; ++n) acc[m][n] = (f32x4){0.f, 0.f, 0.f, 0.f};
#pragma unroll
  for (int kk = 0; kk < 4; ++kk) {
    bf16x8 af[4], bfr[4];
#pragma unroll
    for (int n = 0; n < 4; ++n) {
      int rowv = wc * 64 + n * 16 + (l & 15);
      bfr[n] = *(const bf16x8*)(Wb + (size_t)rowv * 128 + (kk * 4 + (l >> 4)) * 8);
    }
#pragma unroll
    for (int m = 0; m < 4; ++m) {
      int row = wr * 64 + m * 16 + (l & 15);
      int gsw = (kk * 4 + (l >> 4)) ^ (row & 15);
      af[m] = *(const bf16x8*)&Xs[row * 128 + gsw * 8];
    }
#pragma unroll
    for (int m = 0; m < 4; ++m)
#pragma unroll
      for (int n = 0; n < 4; ++n)
        acc[m][n] = __builtin_amdgcn_mfma_f32_16x16x32_bf16(af[m], bfr[n], acc[m][n], 0, 0, 0);
  }
  float part[4][4];
#pragma unroll
  for (int m = 0; m < 4; ++m)
#pragma unroll
    for (int r = 0; r < 4; ++r) part[m][r] = 0.f;
#pragma unroll
  for (int n = 0; n < 4; ++n) {
    int col = wc * 64 + n * 16 + (l & 15);
    float bb = b1[col], w2 = W2[col];
#pragma unroll
    for (int m = 0; m < 4; ++m)
#pragma unroll
      for (int r = 0; r < 4; ++r) {
        float y = fmaxf(acc[m][n][r] + bb, 0.f);
        part[m][r] += y * w2;
      }
  }
#pragma unroll
  for (int d = 1; d < 16; d <<= 1)
#pragma unroll
    for (int m = 0; m < 4; ++m)
#pragma unroll
      for (int r = 0; r < 4; ++r) part[m][r] += __shfl_xor(part[m][r], d);
  __syncthreads();  // safe to alias Xs now
  float* sc = (float*)Xs;
  if ((l & 15) == 0) {
#pragma unroll
    for (int m = 0; m < 4; ++m)
#pragma unroll
      for (int r = 0; r < 4; ++r)
        sc[wc * 128 + wr * 64 + m * 16 + (l >> 4) * 4 + r] = part[m][r];
  }
  __syncthreads();
  if (t < 128 && (MODE == 0 || e0 + t < npairs)) {
    float logit = sc[t] + sc[128 + t] + b2[0];
    out[e0 + t] = sigmoidf(logit);
  }
}

// ---------------- entity segment sums ----------------
__global__ void k_ent_scatter(const float* __restrict__ h3, const float* __restrict__ pos,
                              const int* __restrict__ entity, float* __restrict__ ent_sum,
                              float* __restrict__ pos_sum, float* __restrict__ cnt) {
  int i = blockIdx.x * blockDim.x + threadIdx.x;
  if (i >= N_NODES * 32) return;
  int n = i >> 5, c = i & 31;
  int e = entity[n];
  f32x4 v = *(const f32x4*)(h3 + (size_t)n * 128 + c * 4);
  atomicAdd(&ent_sum[e * 128 + c * 4 + 0], v[0]);
  atomicAdd(&ent_sum[e * 128 + c * 4 + 1], v[1]);
  atomicAdd(&ent_sum[e * 128 + c * 4 + 2], v[2]);
  atomicAdd(&ent_sum[e * 128 + c * 4 + 3], v[3]);
  if (c == 0) {
    atomicAdd(&pos_sum[e * 2 + 0], pos[n * 2 + 0]);
    atomicAdd(&pos_sum[e * 2 + 1], pos[n * 2 + 1]);
    atomicAdd(&cnt[e], 1.f);
  }
}

__global__ void k_entity_states(const float* __restrict__ ent_sum, const float* __restrict__ We,
                                const float* __restrict__ be, float* __restrict__ es) {
  int i = blockIdx.x * blockDim.x + threadIdx.x;
  if (i >= NENT * 128) return;
  int e = i >> 7, j = i & 127;
  const float* x = ent_sum + (size_t)e * 128;
  const float* wrow = We + (size_t)j * 128;
  float s = be[j];
  for (int k = 0; k < 128; k += 4) {
    f32x4 xv = *(const f32x4*)(x + k);
    f32x4 wv = *(const f32x4*)(wrow + k);
    s += xv[0] * wv[0] + xv[1] * wv[1] + xv[2] * wv[2] + xv[3] * wv[3];
  }
  es[i] = s;
}

__global__ void k_entity_class(const float* __restrict__ es, const float* __restrict__ Wc,
                               const float* __restrict__ bc, float* __restrict__ out) {
  int i = blockIdx.x * blockDim.x + threadIdx.x;
  if (i >= NENT * 4) return;
  int e = i >> 2, c = i & 3;
  const float* x = es + (size_t)e * 128;
  const float* wrow = Wc + (size_t)c * 128;
  float s = bc[c];
  for (int k = 0; k < 128; ++k) s += x[k] * wrow[k];
  out[i] = sigmoidf(s);
}

__global__ void k_entity_pos(const float* __restrict__ pos_sum, const float* __restrict__ cnt,
                             float* __restrict__ outpos, float* __restrict__ wspos) {
  int e = blockIdx.x * blockDim.x + threadIdx.x;
  if (e >= NENT) return;
  float c = fmaxf(cnt[e], 1.f);
  float x = pos_sum[e * 2] / c, y = pos_sum[e * 2 + 1] / c;
  outpos[e * 2] = x; outpos[e * 2 + 1] = y;
  wspos[e * 2] = x; wspos[e * 2 + 1] = y;
}

// ---------------- exact knn (K smallest d2, ties -> smaller index) ----------------
__global__ __launch_bounds__(256) void k_knn(const float* __restrict__ entpos,
                                             int* __restrict__ knn) {
  __shared__ float d2row[NENT];
  __shared__ float rv[256];
  __shared__ int ri[256];
  int i = blockIdx.x, t = threadIdx.x;
  float px = entpos[i * 2], py = entpos[i * 2 + 1];
  for (int j = t; j < NENT; j += 256) {
    float dx = px - entpos[j * 2], dy = py - entpos[j * 2 + 1];
    d2row[j] = __fadd_rn(__fmul_rn(dx, dx), __fmul_rn(dy, dy));
  }
  __syncthreads();
  for (int k = 0; k < KNN_K; ++k) {
    float bv = __builtin_inff(); int bi = 0x7fffffff;
    for (int j = t; j < NENT; j += 256) {
      float v = d2row[j];
      if (v < bv) { bv = v; bi = j; }
    }
    rv[t] = bv; ri[t] = bi;
    __syncthreads();
    for (int s = 128; s > 0; s >>= 1) {
      if (t < s) {
        if (rv[t + s] < rv[t] || (rv[t + s] == rv[t] && ri[t + s] < ri[t])) {
          rv[t] = rv[t + s]; ri[t] = ri[t + s];
        }
      }
      __syncthreads();
    }
    if (t == 0) { knn[i * KNN_K + k] = ri[0]; d2row[ri[0]] = __builtin_inff(); }
    __syncthreads();
  }
}

// =======================================================================
extern "C" void kernel_launch(void* const* d_in, const int* in_sizes, int n_in,
                              void* d_out, int out_size, void* d_ws, size_t ws_size,
                              hipStream_t stream) {
  const float* position = (const float*)d_in[0];
  const float* w_embed  = (const float*)d_in[1];
  const int*   src      = (const int*)d_in[2];
  const int*   dst      = (const int*)d_in[3];
  const int*   entity   = (const int*)d_in[4];
  const float* W1 = (const float*)d_in[5];
  const float* al1 = (const float*)d_in[6];
  const float* ar1 = (const float*)d_in[7];
  const float* Wr1 = (const float*)d_in[8];
  const float* W2 = (const float*)d_in[9];
  const float* al2 = (const float*)d_in[10];
  const float* ar2 = (const float*)d_in[11];
  const float* Wr2 = (const float*)d_in[12];
  const float* W3 = (const float*)d_in[13];
  const float* al3 = (const float*)d_in[14];
  const float* ar3 = (const float*)d_in[15];
  const float* Wr3 = (const float*)d_in[16];
  const float* Wg1 = (const float*)d_in[17];
  const float* bg1 = (const float*)d_in[18];
  const float* Wg2 = (const float*)d_in[19];
  const float* bg2 = (const float*)d_in[20];
  const float* We  = (const float*)d_in[21];
  const float* be  = (const float*)d_in[22];
  const float* Wl1 = (const float*)d_in[23];
  const float* bl1 = (const float*)d_in[24];
  const float* Wl2 = (const float*)d_in[25];
  const float* bl2 = (const float*)d_in[26];
  const float* Wc  = (const float*)d_in[27];
  const float* bc  = (const float*)d_in[28];

  float* out_groups = (float*)d_out;
  float* out_class  = out_groups + N_EDGES;
  float* out_pos    = out_class + NENT * 4;
  float* out_link   = out_pos + NENT * 2;

  char* ws = (char*)d_ws;
  size_t off = 0;
  auto carve = [&](size_t bytes) -> char* {
    char* p = ws + off;
    off = (off + bytes + 255) & ~(size_t)255;
    return p;
  };
  // fused GEMM output: [N, 1024] bf16 — cols 0..511 = feat, 512..1023 = hres
  unsigned short* featC = (unsigned short*)carve((size_t)N_NODES * 1024 * 2);
  unsigned short* hA = (unsigned short*)carve((size_t)N_NODES * 512 * 2);
  unsigned short* hB = (unsigned short*)carve((size_t)N_NODES * 512 * 2);
  unsigned short* wbf = (unsigned short*)carve((size_t)1024 * 512 * 2);  // [W;Wr] bf16
  unsigned short* wg1b = (unsigned short*)carve(128 * 128 * 2);
  unsigned short* wl1b = (unsigned short*)carve(128 * 128 * 2);
  float* el = (float*)carve((size_t)N_NODES * 4 * 4);
  float* er = (float*)carve((size_t)N_NODES * 4 * 4);
  int* indeg = (int*)carve((size_t)N_NODES * 4);
  int* indptr = (int*)carve((size_t)(N_NODES + 1) * 4);
  int* cursor = (int*)carve((size_t)N_NODES * 4);
  int* csr_src = (int*)carve((size_t)N_EDGES * 4);
  float* h3 = (float*)carve((size_t)N_NODES * 128 * 4);
  unsigned short* h3b = (unsigned short*)carve((size_t)N_NODES * 128 * 2);
  float* ent_sum = (float*)carve((size_t)NENT * 128 * 4);
  float* pos_sum = (float*)carve((size_t)NENT * 2 * 4);
  float* cnt = (float*)carve((size_t)NENT * 4);
  float* es = (float*)carve((size_t)NENT * 128 * 4);
  unsigned short* esb = (unsigned short*)carve((size_t)NENT * 128 * 2);
  float* wspos = (float*)carve((size_t)NENT * 2 * 4);
  int* knn = (int*)carve((size_t)NENT * KNN_K * 4);

  // ---- CSR over dst (shared by all 3 GAT layers) ----
  hipMemsetAsync(indeg, 0, (size_t)N_NODES * 4, stream);
  k_hist<<<(N_EDGES + 255) / 256, 256, 0, stream>>>(dst, indeg);
  k_scan_fast<<<1, 1024, 0, stream>>>(indeg, indptr, cursor);
  k_scatter<<<(N_EDGES + 255) / 256, 256, 0, stream>>>(src, dst, cursor, csr_src);

  k_build_h0<<<(N_NODES * 128 + 255) / 256, 256, 0, stream>>>(position, w_embed, hA);

  dim3 ggrid((N_NODES + 127) / 128, 8), gblk(256);

  // ---- layer 1 (K=128), fused W|Wr GEMM ----
  k_f2bf<<<(512 * 128 / 4 + 255) / 256, 256, 0, stream>>>(W1, wbf, 512 * 128);
  k_f2bf<<<(512 * 128 / 4 + 255) / 256, 256, 0, stream>>>(Wr1, wbf + 512 * 128, 512 * 128);
  k_gemm_bt<<<ggrid, gblk, 0, stream>>>(hA, wbf, featC, N_NODES, 1024, 128);
  k_el_er<<<5000, 256, 0, stream>>>(featC, 1024, al1, ar1, el, er);
  k_gat_agg<false><<<5000, 256, 0, stream>>>(featC, featC + 512, 1024, el, er, indptr,
                                             csr_src, hB, nullptr, nullptr);

  // ---- layer 2 (K=512) ----
  k_f2bf<<<(512 * 512 / 4 + 255) / 256, 256, 0, stream>>>(W2, wbf, 512 * 512);
  k_f2bf<<<(512 * 512 / 4 + 255) / 256, 256, 0, stream>>>(Wr2, wbf + 512 * 512, 512 * 512);
  k_gemm_bt<<<ggrid, gblk, 0, stream>>>(hB, wbf, featC, N_NODES, 1024, 512);
  k_el_er<<<5000, 256, 0, stream>>>(featC, 1024, al2, ar2, el, er);
  k_gat_agg<false><<<5000, 256, 0, stream>>>(featC, featC + 512, 1024, el, er, indptr,
                                             csr_src, hA, nullptr, nullptr);

  // ---- layer 3 (K=512, no relu, head-mean) ----
  k_f2bf<<<(512 * 512 / 4 + 255) / 256, 256, 0, stream>>>(W3, wbf, 512 * 512);
  k_f2bf<<<(512 * 512 / 4 + 255) / 256, 256, 0, stream>>>(Wr3, wbf + 512 * 512, 512 * 512);
  k_gemm_bt<<<ggrid, gblk, 0, stream>>>(hA, wbf, featC, N_NODES, 1024, 512);
  k_el_er<<<5000, 256, 0, stream>>>(featC, 1024, al3, ar3, el, er);
  k_gat_agg<true><<<5000, 256, 0, stream>>>(featC, featC + 512, 1024, el, er, indptr,
                                            csr_src, nullptr, h3, h3b);

  // ---- groups_score (fused pair MLP on bf16 h3, weights from L2) ----
  k_f2bf<<<(128 * 128 / 4 + 255) / 256, 256, 0, stream>>>(Wg1, wg1b, 128 * 128);
  k_pair_mlp<0><<<N_EDGES / 128, 256, 0, stream>>>(h3b, src, dst, wg1b, bg1, Wg2, bg2,
                                                   out_groups, N_EDGES);

  // ---- entity path ----
  hipMemsetAsync(ent_sum, 0, (size_t)NENT * 128 * 4, stream);
  hipMemsetAsync(pos_sum, 0, (size_t)NENT * 2 * 4, stream);
  hipMemsetAsync(cnt, 0, (size_t)NENT * 4, stream);
  k_ent_scatter<<<(N_NODES * 32 + 255) / 256, 256, 0, stream>>>(h3, position, entity, ent_sum,
                                                                pos_sum, cnt);
  k_entity_states<<<(NENT * 128 + 255) / 256, 256, 0, stream>>>(ent_sum, We, be, es);
  k_entity_class<<<(NENT * 4 + 255) / 256, 256, 0, stream>>>(es, Wc, bc, out_class);
  k_entity_pos<<<(NENT + 255) / 256, 256, 0, stream>>>(pos_sum, cnt, out_pos, wspos);
  k_knn<<<NENT, 256, 0, stream>>>(wspos, knn);
  k_f2bf<<<(NENT * 128 / 4 + 255) / 256, 256, 0, stream>>>(es, esb, NENT * 128);
  k_f2bf<<<(128 * 128 / 4 + 255) / 256, 256, 0, stream>>>(Wl1, wl1b, 128 * 128);
  k_pair_mlp<1><<<(NENT * KNN_K + 127) / 128, 256, 0, stream>>>(esb, knn, nullptr, wl1b, bl1,
                                                                Wl2, bl2, out_link,
                                                                NENT * KNN_K);
}

// Round 6
// 497.388 us; speedup vs baseline: 1.9510x; 1.0477x over previous
//
#include <hip/hip_runtime.h>
#include <math.h>

#define N_NODES 20000
#define N_EDGES 320000
#define NENT    2000
#define KNN_K   10

typedef __attribute__((ext_vector_type(4))) float f32x4;
typedef __attribute__((ext_vector_type(8))) short bf16x8;
typedef __attribute__((ext_vector_type(8))) unsigned short u16x8;
typedef __attribute__((ext_vector_type(4))) unsigned short u16x4;

__device__ __forceinline__ unsigned short f2bf(float f) {
  union { float f; unsigned u; } v; v.f = f;
  unsigned r = v.u + 0x7fffu + ((v.u >> 16) & 1u);
  return (unsigned short)(r >> 16);
}
__device__ __forceinline__ float bf2f(unsigned short u) {
  union { unsigned u; float f; } v; v.u = ((unsigned)u) << 16;
  return v.f;
}
__device__ __forceinline__ float sigmoidf(float x) {
  return 1.f / (1.f + __expf(-x));
}
// async global->LDS, 16B per lane; lds dest = wave-uniform base + lane*16
__device__ __forceinline__ void gload_lds16(const unsigned short* g, unsigned short* lds) {
  __builtin_amdgcn_global_load_lds(
      (const __attribute__((address_space(1))) unsigned int*)g,
      (__attribute__((address_space(3))) unsigned int*)lds, 16, 0, 0);
}

// ---------------- h0 = concat(position, w_embed) -> bf16 ----------------
__global__ void k_build_h0(const float* __restrict__ pos, const float* __restrict__ wemb,
                           unsigned short* __restrict__ h0) {
  int i = blockIdx.x * blockDim.x + threadIdx.x;
  if (i >= N_NODES * 128) return;
  int n = i >> 7, c = i & 127;
  float v = (c < 2) ? pos[n * 2 + c] : wemb[n * 126 + (c - 2)];
  h0[i] = f2bf(v);
}

// ---------------- generic f32 -> bf16 (n multiple of 4) ----------------
__global__ void k_f2bf(const float* __restrict__ in, unsigned short* __restrict__ out, int n) {
  int i = blockIdx.x * blockDim.x + threadIdx.x;
  if (i * 4 >= n) return;
  f32x4 v = *(const f32x4*)(in + i * 4);
  u16x4 o;
  o[0] = f2bf(v[0]); o[1] = f2bf(v[1]); o[2] = f2bf(v[2]); o[3] = f2bf(v[3]);
  *(u16x4*)(out + i * 4) = o;
}

// ------- bf16 MFMA GEMM: C[M,Nc] = A[M,K] * B[Nc,K]^T, bf16 out, stride Nc -------
__global__ __launch_bounds__(256) void k_gemm_bt(
    const unsigned short* __restrict__ A, const unsigned short* __restrict__ B,
    unsigned short* __restrict__ C, int M, int Nc, int K) {
  __shared__ __align__(16) unsigned short As[128 * 64];
  __shared__ __align__(16) unsigned short Bs[128 * 64];
  const int bm = blockIdx.x * 128, bn = blockIdx.y * 128;
  const int t = threadIdx.x;
  const int l = t & 63, w = t >> 6;
  const int wr = w >> 1, wc = w & 1;
  f32x4 acc[4][4];
#pragma unroll
  for (int m = 0; m < 4; ++m)
#pragma unroll
    for (int n = 0; n < 4; ++n) acc[m][n] = (f32x4){0.f, 0.f, 0.f, 0.f};

  for (int kb = 0; kb < K; kb += 64) {
    __syncthreads();
#pragma unroll
    for (int i = 0; i < 4; ++i) {
      int c = t + 256 * i;         // 1024 16B-chunks per tile
      int row = c >> 3, cc = c & 7;
      int scc = cc ^ (row & 7);    // pre-swizzled SOURCE granule (read side keeps same XOR)
      int ar = bm + row; if (ar > M - 1) ar = M - 1;
      gload_lds16(A + (size_t)ar * K + kb + scc * 8, &As[(size_t)(w * 64 + 256 * i) * 8]);
      gload_lds16(B + (size_t)(bn + row) * K + kb + scc * 8,
                  &Bs[(size_t)(w * 64 + 256 * i) * 8]);
    }
    __syncthreads();
#pragma unroll
    for (int kk = 0; kk < 2; ++kk) {
      bf16x8 af[4], bfr[4];
#pragma unroll
      for (int m = 0; m < 4; ++m) {
        int row = wr * 64 + m * 16 + (l & 15);
        int g = (kk * 4 + (l >> 4)) ^ (row & 7);
        af[m] = *(const bf16x8*)&As[row * 64 + g * 8];
      }
#pragma unroll
      for (int n = 0; n < 4; ++n) {
        int row = wc * 64 + n * 16 + (l & 15);
        int g = (kk * 4 + (l >> 4)) ^ (row & 7);
        bfr[n] = *(const bf16x8*)&Bs[row * 64 + g * 8];
      }
#pragma unroll
      for (int m = 0; m < 4; ++m)
#pragma unroll
        for (int n = 0; n < 4; ++n)
          acc[m][n] = __builtin_amdgcn_mfma_f32_16x16x32_bf16(af[m], bfr[n], acc[m][n], 0, 0, 0);
    }
  }
#pragma unroll
  for (int m = 0; m < 4; ++m) {
    int r0 = bm + wr * 64 + m * 16 + ((l >> 4) << 2);
#pragma unroll
    for (int n = 0; n < 4; ++n) {
      int c0 = bn + wc * 64 + n * 16 + (l & 15);
#pragma unroll
      for (int r = 0; r < 4; ++r) {
        int row = r0 + r;
        if (row < M) C[(size_t)row * Nc + c0] = f2bf(acc[m][n][r]);
      }
    }
  }
}

// ---------------- el/er: per (node, head) dot(feat, al/ar) ----------------
__global__ void k_el_er(const unsigned short* __restrict__ feat, int fstride,
                        const float* __restrict__ al, const float* __restrict__ ar,
                        float* __restrict__ el, float* __restrict__ er) {
  int wid = (blockIdx.x * blockDim.x + threadIdx.x) >> 6;
  if (wid >= N_NODES) return;
  int l = threadIdx.x & 63;
  int g = l >> 4, q = l & 15;
  u16x8 fv = *(const u16x8*)(feat + (size_t)wid * fstride + l * 8);
  const float* alp = al + g * 128 + q * 8;
  const float* arp = ar + g * 128 + q * 8;
  float sl = 0.f, sr = 0.f;
#pragma unroll
  for (int j = 0; j < 8; ++j) { float f = bf2f(fv[j]); sl += f * alp[j]; sr += f * arp[j]; }
#pragma unroll
  for (int d = 1; d < 16; d <<= 1) { sl += __shfl_xor(sl, d); sr += __shfl_xor(sr, d); }
  if (q == 0) { el[wid * 4 + g] = sl; er[wid * 4 + g] = sr; }
}

// ---------------- CSR build ----------------
__global__ void k_hist(const int* __restrict__ dst, int* __restrict__ indeg) {
  int e = blockIdx.x * blockDim.x + threadIdx.x;
  if (e < N_EDGES) atomicAdd(&indeg[dst[e]], 1);
}

__global__ __launch_bounds__(1024) void k_scan_fast(const int* __restrict__ indeg,
                                                    int* __restrict__ indptr,
                                                    int* __restrict__ cursor) {
  __shared__ int wsum[16];
  const int t = threadIdx.x;
  const int l = t & 63, w = t >> 6;
  const int CH = 20;  // 1024*20 >= 20000
  int base = t * CH;
  int vals[CH];
  int s = 0;
#pragma unroll
  for (int i = 0; i < CH; ++i) {
    int idx = base + i;
    int v = (idx < N_NODES) ? indeg[idx] : 0;
    vals[i] = v;
    s += v;
  }
  int ss = s;
#pragma unroll
  for (int d = 1; d < 64; d <<= 1) { int o = __shfl_up(ss, d); if (l >= d) ss += o; }
  if (l == 63) wsum[w] = ss;
  __syncthreads();
  if (t < 16) {
    int v = wsum[t];
#pragma unroll
    for (int d = 1; d < 16; d <<= 1) { int o = __shfl_up(v, d); if (t >= d) v += o; }
    wsum[t] = v;
  }
  __syncthreads();
  int run = ((w > 0) ? wsum[w - 1] : 0) + ss - s;
  if (t == 0) indptr[0] = 0;
#pragma unroll
  for (int i = 0; i < CH; ++i) {
    int idx = base + i;
    if (idx < N_NODES) {
      cursor[idx] = run;
      run += vals[i];
      indptr[idx + 1] = run;
    }
  }
}

__global__ void k_scatter(const int* __restrict__ src, const int* __restrict__ dst,
                          int* __restrict__ cursor, int* __restrict__ csr_src) {
  int e = blockIdx.x * blockDim.x + threadIdx.x;
  if (e < N_EDGES) {
    int p = atomicAdd(&cursor[dst[e]], 1);
    csr_src[p] = src[e];
  }
}

// ---------------- GAT edge-softmax + aggregation (wave per dst node) ----------------
// pass 2 manually 4-way unrolled: independent gathers in flight (latency hiding)
template <bool FINAL>
__global__ void k_gat_agg(const unsigned short* __restrict__ feat,
                          const unsigned short* __restrict__ hres, int fstride,
                          const float* __restrict__ el, const float* __restrict__ er,
                          const int* __restrict__ indptr, const int* __restrict__ csr_src,
                          unsigned short* __restrict__ hnext, float* __restrict__ h3,
                          unsigned short* __restrict__ h3b) {
  int wid = (blockIdx.x * blockDim.x + threadIdx.x) >> 6;
  if (wid >= N_NODES) return;
  int l = threadIdx.x & 63;
  int g = l >> 4;
  int beg = indptr[wid], end = indptr[wid + 1];
  f32x4 er4 = *(const f32x4*)(er + wid * 4);
  const float NI = -__builtin_inff();
  f32x4 mx = (f32x4){NI, NI, NI, NI};
  for (int j = beg + l; j < end; j += 64) {
    int s = csr_src[j];
    f32x4 el4 = *(const f32x4*)(el + s * 4);
#pragma unroll
    for (int h = 0; h < 4; ++h) {
      float v = el4[h] + er4[h];
      v = (v >= 0.f) ? v : 0.2f * v;
      mx[h] = fmaxf(mx[h], v);
    }
  }
#pragma unroll
  for (int d = 1; d < 64; d <<= 1) {
#pragma unroll
    for (int h = 0; h < 4; ++h) mx[h] = fmaxf(mx[h], __shfl_xor(mx[h], d));
  }
  float m_g = mx[g];
  float er_g = er4[g];
  float asum = 0.f;
  float acc[8];
#pragma unroll
  for (int j2 = 0; j2 < 8; ++j2) acc[j2] = 0.f;
  const unsigned short* fbase = feat + l * 8;
  int j = beg;
  for (; j + 4 <= end; j += 4) {
    int s0 = csr_src[j + 0], s1 = csr_src[j + 1];
    int s2 = csr_src[j + 2], s3 = csr_src[j + 3];
    float q0 = el[s0 * 4 + g], q1 = el[s1 * 4 + g];
    float q2 = el[s2 * 4 + g], q3 = el[s3 * 4 + g];
    u16x8 f0 = *(const u16x8*)(fbase + (size_t)s0 * fstride);
    u16x8 f1 = *(const u16x8*)(fbase + (size_t)s1 * fstride);
    u16x8 f2 = *(const u16x8*)(fbase + (size_t)s2 * fstride);
    u16x8 f3 = *(const u16x8*)(fbase + (size_t)s3 * fstride);
    float e0 = q0 + er_g; e0 = (e0 >= 0.f) ? e0 : 0.2f * e0;
    float e1 = q1 + er_g; e1 = (e1 >= 0.f) ? e1 : 0.2f * e1;
    float e2 = q2 + er_g; e2 = (e2 >= 0.f) ? e2 : 0.2f * e2;
    float e3 = q3 + er_g; e3 = (e3 >= 0.f) ? e3 : 0.2f * e3;
    float p0 = __expf(e0 - m_g), p1 = __expf(e1 - m_g);
    float p2 = __expf(e2 - m_g), p3 = __expf(e3 - m_g);
    asum += (p0 + p1) + (p2 + p3);
#pragma unroll
    for (int k = 0; k < 8; ++k)
      acc[k] += p0 * bf2f(f0[k]) + p1 * bf2f(f1[k]) + p2 * bf2f(f2[k]) + p3 * bf2f(f3[k]);
  }
  for (; j < end; ++j) {
    int s = csr_src[j];
    float ev = el[s * 4 + g] + er_g;
    ev = (ev >= 0.f) ? ev : 0.2f * ev;
    float p = __expf(ev - m_g);
    asum += p;
    u16x8 fv = *(const u16x8*)(fbase + (size_t)s * fstride);
#pragma unroll
    for (int k = 0; k < 8; ++k) acc[k] += p * bf2f(fv[k]);
  }
  float inv = (end > beg) ? 1.f / asum : 1.f;
  u16x8 hv = *(const u16x8*)(hres + (size_t)wid * fstride + l * 8);
  float o[8];
#pragma unroll
  for (int k = 0; k < 8; ++k) o[k] = acc[k] * inv + bf2f(hv[k]);
  if constexpr (!FINAL) {
    u16x8 ob;
#pragma unroll
    for (int k = 0; k < 8; ++k) ob[k] = f2bf(fmaxf(o[k], 0.f));
    *(u16x8*)(hnext + (size_t)wid * 512 + l * 8) = ob;
  } else {
#pragma unroll
    for (int k = 0; k < 8; ++k) {
      float v = o[k];
      v += __shfl_xor(v, 16);
      v += __shfl_xor(v, 32);
      o[k] = v * 0.25f;
    }
    if (g == 0) {
      f32x4 o0 = (f32x4){o[0], o[1], o[2], o[3]};
      f32x4 o1 = (f32x4){o[4], o[5], o[6], o[7]};
      *(f32x4*)(h3 + (size_t)wid * 128 + l * 8) = o0;
      *(f32x4*)(h3 + (size_t)wid * 128 + l * 8 + 4) = o1;
      u16x8 hb;
#pragma unroll
      for (int k = 0; k < 8; ++k) hb[k] = f2bf(o[k]);
      *(u16x8*)(h3b + (size_t)wid * 128 + l * 8) = hb;
    }
  }
}

// ---- fused pair MLP: sigmoid(relu(|X[a]-X[b]| @ W1^T + b1) @ W2^T + b2) ----
template <int MODE>
__global__ __launch_bounds__(256) void k_pair_mlp(
    const unsigned short* __restrict__ X, const int* __restrict__ ia,
    const int* __restrict__ ib, const unsigned short* __restrict__ Wb,
    const float* __restrict__ b1, const float* __restrict__ W2,
    const float* __restrict__ b2, float* __restrict__ out, int npairs) {
  __shared__ __align__(16) unsigned short Xs[128 * 128];
  const int t = threadIdx.x;
  const int l = t & 63, w = t >> 6, wr = w >> 1, wc = w & 1;
  const int e0 = blockIdx.x * 128;
  {
    int r = t >> 1, hf = t & 1;
    int e = e0 + r;
    if (MODE == 1 && e >= npairs) e = npairs - 1;
    int sa, sb;
    if (MODE == 0) { sa = ia[e]; sb = ib[e]; }
    else           { sa = ia[e]; sb = e / KNN_K; }
    const unsigned short* pa = X + (size_t)sa * 128 + hf * 64;
    const unsigned short* pb = X + (size_t)sb * 128 + hf * 64;
#pragma unroll
    for (int c = 0; c < 64; c += 8) {
      u16x8 av = *(const u16x8*)(pa + c);
      u16x8 bv = *(const u16x8*)(pb + c);
      u16x8 xv;
#pragma unroll
      for (int j = 0; j < 8; ++j) xv[j] = f2bf(fabsf(bf2f(av[j]) - bf2f(bv[j])));
      int gb = hf * 8 + (c >> 3);
      *(u16x8*)&Xs[r * 128 + (gb ^ (r & 15)) * 8] = xv;
    }
  }
  __syncthreads();
  f32x4 acc[4][4];
#pragma unroll
  for (int m = 0; m < 4; ++m)
#pragma unroll
    for (int n = 0; n < 4; ++n) acc[m][n] = (f32x4){0.f, 0.f, 0.f, 0.f};
#pragma unroll
  for (int kk = 0; kk < 4; ++kk) {
    bf16x8 af[4], bfr[4];
#pragma unroll
    for (int n = 0; n < 4; ++n) {
      int rowv = wc * 64 + n * 16 + (l & 15);
      bfr[n] = *(const bf16x8*)(Wb + (size_t)rowv * 128 + (kk * 4 + (l >> 4)) * 8);
    }
#pragma unroll
    for (int m = 0; m < 4; ++m) {
      int row = wr * 64 + m * 16 + (l & 15);
      int gsw = (kk * 4 + (l >> 4)) ^ (row & 15);
      af[m] = *(const bf16x8*)&Xs[row * 128 + gsw * 8];
    }
#pragma unroll
    for (int m = 0; m < 4; ++m)
#pragma unroll
      for (int n = 0; n < 4; ++n)
        acc[m][n] = __builtin_amdgcn_mfma_f32_16x16x32_bf16(af[m], bfr[n], acc[m][n], 0, 0, 0);
  }
  float part[4][4];
#pragma unroll
  for (int m = 0; m < 4; ++m)
#pragma unroll
    for (int r = 0; r < 4; ++r) part[m][r] = 0.f;
#pragma unroll
  for (int n = 0; n < 4; ++n) {
    int col = wc * 64 + n * 16 + (l & 15);
    float bb = b1[col], w2 = W2[col];
#pragma unroll
    for (int m = 0; m < 4; ++m)
#pragma unroll
      for (int r = 0; r < 4; ++r) {
        float y = fmaxf(acc[m][n][r] + bb, 0.f);
        part[m][r] += y * w2;
      }
  }
#pragma unroll
  for (int d = 1; d < 16; d <<= 1)
#pragma unroll
    for (int m = 0; m < 4; ++m)
#pragma unroll
      for (int r = 0; r < 4; ++r) part[m][r] += __shfl_xor(part[m][r], d);
  __syncthreads();  // safe to alias Xs now
  float* sc = (float*)Xs;
  if ((l & 15) == 0) {
#pragma unroll
    for (int m = 0; m < 4; ++m)
#pragma unroll
      for (int r = 0; r < 4; ++r)
        sc[wc * 128 + wr * 64 + m * 16 + (l >> 4) * 4 + r] = part[m][r];
  }
  __syncthreads();
  if (t < 128 && (MODE == 0 || e0 + t < npairs)) {
    float logit = sc[t] + sc[128 + t] + b2[0];
    out[e0 + t] = sigmoidf(logit);
  }
}

// ---------------- entity segment sums ----------------
__global__ void k_ent_scatter(const float* __restrict__ h3, const float* __restrict__ pos,
                              const int* __restrict__ entity, float* __restrict__ ent_sum,
                              float* __restrict__ pos_sum, float* __restrict__ cnt) {
  int i = blockIdx.x * blockDim.x + threadIdx.x;
  if (i >= N_NODES * 32) return;
  int n = i >> 5, c = i & 31;
  int e = entity[n];
  f32x4 v = *(const f32x4*)(h3 + (size_t)n * 128 + c * 4);
  atomicAdd(&ent_sum[e * 128 + c * 4 + 0], v[0]);
  atomicAdd(&ent_sum[e * 128 + c * 4 + 1], v[1]);
  atomicAdd(&ent_sum[e * 128 + c * 4 + 2], v[2]);
  atomicAdd(&ent_sum[e * 128 + c * 4 + 3], v[3]);
  if (c == 0) {
    atomicAdd(&pos_sum[e * 2 + 0], pos[n * 2 + 0]);
    atomicAdd(&pos_sum[e * 2 + 1], pos[n * 2 + 1]);
    atomicAdd(&cnt[e], 1.f);
  }
}

__global__ void k_entity_states(const float* __restrict__ ent_sum, const float* __restrict__ We,
                                const float* __restrict__ be, float* __restrict__ es) {
  int i = blockIdx.x * blockDim.x + threadIdx.x;
  if (i >= NENT * 128) return;
  int e = i >> 7, j = i & 127;
  const float* x = ent_sum + (size_t)e * 128;
  const float* wrow = We + (size_t)j * 128;
  float s = be[j];
  for (int k = 0; k < 128; k += 4) {
    f32x4 xv = *(const f32x4*)(x + k);
    f32x4 wv = *(const f32x4*)(wrow + k);
    s += xv[0] * wv[0] + xv[1] * wv[1] + xv[2] * wv[2] + xv[3] * wv[3];
  }
  es[i] = s;
}

__global__ void k_entity_class(const float* __restrict__ es, const float* __restrict__ Wc,
                               const float* __restrict__ bc, float* __restrict__ out) {
  int i = blockIdx.x * blockDim.x + threadIdx.x;
  if (i >= NENT * 4) return;
  int e = i >> 2, c = i & 3;
  const float* x = es + (size_t)e * 128;
  const float* wrow = Wc + (size_t)c * 128;
  float s = bc[c];
  for (int k = 0; k < 128; ++k) s += x[k] * wrow[k];
  out[i] = sigmoidf(s);
}

__global__ void k_entity_pos(const float* __restrict__ pos_sum, const float* __restrict__ cnt,
                             float* __restrict__ outpos, float* __restrict__ wspos) {
  int e = blockIdx.x * blockDim.x + threadIdx.x;
  if (e >= NENT) return;
  float c = fmaxf(cnt[e], 1.f);
  float x = pos_sum[e * 2] / c, y = pos_sum[e * 2 + 1] / c;
  outpos[e * 2] = x; outpos[e * 2 + 1] = y;
  wspos[e * 2] = x; wspos[e * 2 + 1] = y;
}

// ---------------- exact knn (K smallest d2, ties -> smaller index) ----------------
__global__ __launch_bounds__(256) void k_knn(const float* __restrict__ entpos,
                                             int* __restrict__ knn) {
  __shared__ float d2row[NENT];
  __shared__ float rv[256];
  __shared__ int ri[256];
  int i = blockIdx.x, t = threadIdx.x;
  float px = entpos[i * 2], py = entpos[i * 2 + 1];
  for (int j = t; j < NENT; j += 256) {
    float dx = px - entpos[j * 2], dy = py - entpos[j * 2 + 1];
    d2row[j] = __fadd_rn(__fmul_rn(dx, dx), __fmul_rn(dy, dy));
  }
  __syncthreads();
  for (int k = 0; k < KNN_K; ++k) {
    float bv = __builtin_inff(); int bi = 0x7fffffff;
    for (int j = t; j < NENT; j += 256) {
      float v = d2row[j];
      if (v < bv) { bv = v; bi = j; }
    }
    rv[t] = bv; ri[t] = bi;
    __syncthreads();
    for (int s = 128; s > 0; s >>= 1) {
      if (t < s) {
        if (rv[t + s] < rv[t] || (rv[t + s] == rv[t] && ri[t + s] < ri[t])) {
          rv[t] = rv[t + s]; ri[t] = ri[t + s];
        }
      }
      __syncthreads();
    }
    if (t == 0) { knn[i * KNN_K + k] = ri[0]; d2row[ri[0]] = __builtin_inff(); }
    __syncthreads();
  }
}

// =======================================================================
extern "C" void kernel_launch(void* const* d_in, const int* in_sizes, int n_in,
                              void* d_out, int out_size, void* d_ws, size_t ws_size,
                              hipStream_t stream) {
  const float* position = (const float*)d_in[0];
  const float* w_embed  = (const float*)d_in[1];
  const int*   src      = (const int*)d_in[2];
  const int*   dst      = (const int*)d_in[3];
  const int*   entity   = (const int*)d_in[4];
  const float* W1 = (const float*)d_in[5];
  const float* al1 = (const float*)d_in[6];
  const float* ar1 = (const float*)d_in[7];
  const float* Wr1 = (const float*)d_in[8];
  const float* W2 = (const float*)d_in[9];
  const float* al2 = (const float*)d_in[10];
  const float* ar2 = (const float*)d_in[11];
  const float* Wr2 = (const float*)d_in[12];
  const float* W3 = (const float*)d_in[13];
  const float* al3 = (const float*)d_in[14];
  const float* ar3 = (const float*)d_in[15];
  const float* Wr3 = (const float*)d_in[16];
  const float* Wg1 = (const float*)d_in[17];
  const float* bg1 = (const float*)d_in[18];
  const float* Wg2 = (const float*)d_in[19];
  const float* bg2 = (const float*)d_in[20];
  const float* We  = (const float*)d_in[21];
  const float* be  = (const float*)d_in[22];
  const float* Wl1 = (const float*)d_in[23];
  const float* bl1 = (const float*)d_in[24];
  const float* Wl2 = (const float*)d_in[25];
  const float* bl2 = (const float*)d_in[26];
  const float* Wc  = (const float*)d_in[27];
  const float* bc  = (const float*)d_in[28];

  float* out_groups = (float*)d_out;
  float* out_class  = out_groups + N_EDGES;
  float* out_pos    = out_class + NENT * 4;
  float* out_link   = out_pos + NENT * 2;

  char* ws = (char*)d_ws;
  size_t off = 0;
  auto carve = [&](size_t bytes) -> char* {
    char* p = ws + off;
    off = (off + bytes + 255) & ~(size_t)255;
    return p;
  };
  // fused GEMM output: [N, 1024] bf16 — cols 0..511 = feat, 512..1023 = hres
  unsigned short* featC = (unsigned short*)carve((size_t)N_NODES * 1024 * 2);
  unsigned short* hA = (unsigned short*)carve((size_t)N_NODES * 512 * 2);
  unsigned short* hB = (unsigned short*)carve((size_t)N_NODES * 512 * 2);
  unsigned short* wbf = (unsigned short*)carve((size_t)1024 * 512 * 2);  // [W;Wr] bf16
  unsigned short* wg1b = (unsigned short*)carve(128 * 128 * 2);
  unsigned short* wl1b = (unsigned short*)carve(128 * 128 * 2);
  float* el = (float*)carve((size_t)N_NODES * 4 * 4);
  float* er = (float*)carve((size_t)N_NODES * 4 * 4);
  int* indeg = (int*)carve((size_t)N_NODES * 4);
  int* indptr = (int*)carve((size_t)(N_NODES + 1) * 4);
  int* cursor = (int*)carve((size_t)N_NODES * 4);
  int* csr_src = (int*)carve((size_t)N_EDGES * 4);
  float* h3 = (float*)carve((size_t)N_NODES * 128 * 4);
  unsigned short* h3b = (unsigned short*)carve((size_t)N_NODES * 128 * 2);
  float* ent_sum = (float*)carve((size_t)NENT * 128 * 4);
  float* pos_sum = (float*)carve((size_t)NENT * 2 * 4);
  float* cnt = (float*)carve((size_t)NENT * 4);
  float* es = (float*)carve((size_t)NENT * 128 * 4);
  unsigned short* esb = (unsigned short*)carve((size_t)NENT * 128 * 2);
  float* wspos = (float*)carve((size_t)NENT * 2 * 4);
  int* knn = (int*)carve((size_t)NENT * KNN_K * 4);

  // ---- CSR over dst (shared by all 3 GAT layers) ----
  hipMemsetAsync(indeg, 0, (size_t)N_NODES * 4, stream);
  k_hist<<<(N_EDGES + 255) / 256, 256, 0, stream>>>(dst, indeg);
  k_scan_fast<<<1, 1024, 0, stream>>>(indeg, indptr, cursor);
  k_scatter<<<(N_EDGES + 255) / 256, 256, 0, stream>>>(src, dst, cursor, csr_src);

  k_build_h0<<<(N_NODES * 128 + 255) / 256, 256, 0, stream>>>(position, w_embed, hA);

  dim3 ggrid((N_NODES + 127) / 128, 8), gblk(256);

  // ---- layer 1 (K=128), fused W|Wr GEMM ----
  k_f2bf<<<(512 * 128 / 4 + 255) / 256, 256, 0, stream>>>(W1, wbf, 512 * 128);
  k_f2bf<<<(512 * 128 / 4 + 255) / 256, 256, 0, stream>>>(Wr1, wbf + 512 * 128, 512 * 128);
  k_gemm_bt<<<ggrid, gblk, 0, stream>>>(hA, wbf, featC, N_NODES, 1024, 128);
  k_el_er<<<5000, 256, 0, stream>>>(featC, 1024, al1, ar1, el, er);
  k_gat_agg<false><<<5000, 256, 0, stream>>>(featC, featC + 512, 1024, el, er, indptr,
                                             csr_src, hB, nullptr, nullptr);

  // ---- layer 2 (K=512) ----
  k_f2bf<<<(512 * 512 / 4 + 255) / 256, 256, 0, stream>>>(W2, wbf, 512 * 512);
  k_f2bf<<<(512 * 512 / 4 + 255) / 256, 256, 0, stream>>>(Wr2, wbf + 512 * 512, 512 * 512);
  k_gemm_bt<<<ggrid, gblk, 0, stream>>>(hB, wbf, featC, N_NODES, 1024, 512);
  k_el_er<<<5000, 256, 0, stream>>>(featC, 1024, al2, ar2, el, er);
  k_gat_agg<false><<<5000, 256, 0, stream>>>(featC, featC + 512, 1024, el, er, indptr,
                                             csr_src, hA, nullptr, nullptr);

  // ---- layer 3 (K=512, no relu, head-mean) ----
  k_f2bf<<<(512 * 512 / 4 + 255) / 256, 256, 0, stream>>>(W3, wbf, 512 * 512);
  k_f2bf<<<(512 * 512 / 4 + 255) / 256, 256, 0, stream>>>(Wr3, wbf + 512 * 512, 512 * 512);
  k_gemm_bt<<<ggrid, gblk, 0, stream>>>(hA, wbf, featC, N_NODES, 1024, 512);
  k_el_er<<<5000, 256, 0, stream>>>(featC, 1024, al3, ar3, el, er);
  k_gat_agg<true><<<5000, 256, 0, stream>>>(featC, featC + 512, 1024, el, er, indptr,
                                            csr_src, nullptr, h3, h3b);

  // ---- groups_score (fused pair MLP on bf16 h3, weights from L2) ----
  k_f2bf<<<(128 * 128 / 4 + 255) / 256, 256, 0, stream>>>(Wg1, wg1b, 128 * 128);
  k_pair_mlp<0><<<N_EDGES / 128, 256, 0, stream>>>(h3b, src, dst, wg1b, bg1, Wg2, bg2,
                                                   out_groups, N_EDGES);

  // ---- entity path ----
  hipMemsetAsync(ent_sum, 0, (size_t)NENT * 128 * 4, stream);
  hipMemsetAsync(pos_sum, 0, (size_t)NENT * 2 * 4, stream);
  hipMemsetAsync(cnt, 0, (size_t)NENT * 4, stream);
  k_ent_scatter<<<(N_NODES * 32 + 255) / 256, 256, 0, stream>>>(h3, position, entity, ent_sum,
                                                                pos_sum, cnt);
  k_entity_states<<<(NENT * 128 + 255) / 256, 256, 0, stream>>>(ent_sum, We, be, es);
  k_entity_class<<<(NENT * 4 + 255) / 256, 256, 0, stream>>>(es, Wc, bc, out_class);
  k_entity_pos<<<(NENT + 255) / 256, 256, 0, stream>>>(pos_sum, cnt, out_pos, wspos);
  k_knn<<<NENT, 256, 0, stream>>>(wspos, knn);
  k_f2bf<<<(NENT * 128 / 4 + 255) / 256, 256, 0, stream>>>(es, esb, NENT * 128);
  k_f2bf<<<(128 * 128 / 4 + 255) / 256, 256, 0, stream>>>(Wl1, wl1b, 128 * 128);
  k_pair_mlp<1><<<(NENT * KNN_K + 127) / 128, 256, 0, stream>>>(esb, knn, nullptr, wl1b, bl1,
                                                                Wl2, bl2, out_link,
                                                                NENT * KNN_K);
}